// Round 11
// baseline (436.387 us; speedup 1.0000x reference)
//
#include <hip/hip_runtime.h>

// GCN decoder. Atomic-free CSR build (two-level counting sort) ->
// GEMM1(MFMA bf16-split) -> XCD-feature-sliced agg128 (z1) -> GEMM2(MFMA) ->
// agg64+matvec(W3) -> final scalar agg (batched gathers).
// Round 11: slice-per-XCD-pair binding cuts agg128 L2-fill from 8x51MB to
// ~4x2x12.8MB; EBLK 1024 for CSR-build parallelism; aggfin 16-deep MLP.

constexpr int D0 = 256, D1 = 128, D2 = 64;
constexpr int NB = 1024;   // coarse bins
constexpr int BSH = 7;     // bin = key >> 7 (128 nodes per bin)
constexpr int EBLK = 1024; // edges per block in hist/partition kernels

typedef __attribute__((ext_vector_type(2))) float f32x2;
typedef __attribute__((ext_vector_type(4))) float f32x4;
typedef __attribute__((ext_vector_type(8))) short short8;

__device__ inline unsigned short f2bf(float f) {
  unsigned u = __builtin_bit_cast(unsigned, f);
  u += 0x7fffu + ((u >> 16) & 1u);
  return (unsigned short)(u >> 16);
}
__device__ inline float bf2f(unsigned short h) {
  unsigned u = ((unsigned)h) << 16;
  return __builtin_bit_cast(float, u);
}
__device__ inline int rdlane_i(int v, int l) { return __builtin_amdgcn_readlane(v, l); }
__device__ inline float rdlane_f(float v, int l) {
  return __builtin_bit_cast(float, __builtin_amdgcn_readlane(__builtin_bit_cast(int, v), l));
}

// ---------------- merged coarse histograms: src and dst in one edge pass ----------------
__global__ void k_chist2(const int* __restrict__ src, const int* __restrict__ dst,
                         int* __restrict__ bc_s, int* __restrict__ bc_d, int E) {
  __shared__ int hs[NB], hd[NB];
  for (int i = threadIdx.x; i < NB; i += 256) { hs[i] = 0; hd[i] = 0; }
  __syncthreads();
  int e0 = blockIdx.x * EBLK, e1 = min(e0 + EBLK, E);
  for (int i = e0 + threadIdx.x; i < e1; i += 256) {
    atomicAdd(&hs[src[i] >> BSH], 1);
    atomicAdd(&hd[dst[i] >> BSH], 1);
  }
  __syncthreads();
  for (int i = threadIdx.x; i < NB; i += 256) {
    bc_s[blockIdx.x * NB + i] = hs[i];
    bc_d[blockIdx.x * NB + i] = hd[i];
  }
}

// ---------------- coalesced column scan: block = 16 consecutive bins ----------------
__global__ void k_binscan(int* __restrict__ bc_s, int* __restrict__ bt_s,
                          int* __restrict__ bc_d, int* __restrict__ bt_d, int nbk) {
  __shared__ int part[16][17];
  int* bc = blockIdx.y ? bc_d : bc_s;
  int* bt = blockIdx.y ? bt_d : bt_s;
  const int j = threadIdx.x & 15;
  const int c = threadIdx.x >> 4;
  const int bin = blockIdx.x * 16 + j;
  const int chunk = (nbk + 15) / 16;
  const int r0 = c * chunk, r1 = min(r0 + chunk, nbk);
  int s = 0;
  for (int b = r0; b < r1; ++b) s += bc[b * NB + bin];
  part[c][j] = s;
  __syncthreads();
  int pre = 0;
  for (int q = 0; q < c; ++q) pre += part[q][j];
  int run = pre;
  for (int b = r0; b < r1; ++b) {
    int v = bc[b * NB + bin];
    bc[b * NB + bin] = run;
    run += v;
  }
  if (c == 15) bt[bin] = run;
}

// ---------------- scan of 1024 bin totals (block 0: src, block 1: dst) ----------------
__global__ void k_btscan(const int* __restrict__ bt_s, int* __restrict__ cbase_s,
                         const int* __restrict__ bt_d, int* __restrict__ cbase_d,
                         int* __restrict__ offs_end, int E) {
  __shared__ int wsum[16];
  const int* bt = blockIdx.x ? bt_d : bt_s;
  int* cbase = blockIdx.x ? cbase_d : cbase_s;
  int tid = threadIdx.x, lane = tid & 63, wid = tid >> 6;
  int v = bt[tid];
  int x = v;
#pragma unroll
  for (int d = 1; d < 64; d <<= 1) { int t = __shfl_up(x, d); if (lane >= d) x += t; }
  if (lane == 63) wsum[wid] = x;
  __syncthreads();
  if (wid == 0 && lane < 16) {
    int s = wsum[lane];
#pragma unroll
    for (int d = 1; d < 16; d <<= 1) { int t = __shfl_up(s, d, 16); if (lane >= d) s += t; }
    wsum[lane] = s;
  }
  __syncthreads();
  int excl = x - v + (wid ? wsum[wid - 1] : 0);
  cbase[tid] = excl;
  if (tid == NB - 1) cbase[NB] = E;
  if (blockIdx.x == 1 && tid == 0) *offs_end = E;
}

// ---------------- merged coarse partition: one edge pass, both sides ----------------
__global__ void k_cpart2(const int* __restrict__ src, const int* __restrict__ dst,
                         const float* __restrict__ ew,
                         const int* __restrict__ bc_s, const int* __restrict__ cbase_s,
                         const int* __restrict__ bc_d, const int* __restrict__ cbase_d,
                         int* __restrict__ recs_s, int2* __restrict__ recs_d, int E) {
  __shared__ int cs[NB], cd[NB];
  for (int i = threadIdx.x; i < NB; i += 256) {
    cs[i] = cbase_s[i] + bc_s[blockIdx.x * NB + i];
    cd[i] = cbase_d[i] + bc_d[blockIdx.x * NB + i];
  }
  __syncthreads();
  int e0 = blockIdx.x * EBLK, e1 = min(e0 + EBLK, E);
  for (int i = e0 + threadIdx.x; i < e1; i += 256) {
    int s = src[i], d = dst[i];
    int ps = atomicAdd(&cs[s >> BSH], 1);
    recs_s[ps] = s;
    int pd = atomicAdd(&cd[d >> BSH], 1);
    recs_d[pd] = int2{s | ((d & 127) << 17), __builtin_bit_cast(int, ew[i])};
  }
}

// ---------------- merged fine pass: dst CSR (offs, nd, esw) + src hist (ns) ----------------
__global__ void k_finecomb(const int2* __restrict__ recs_d, const int* __restrict__ cbase_d,
                           const int* __restrict__ recs_s, const int* __restrict__ cbase_s,
                           int2* __restrict__ esw, int* __restrict__ offs,
                           float* __restrict__ nd, float* __restrict__ ns, int N) {
  __shared__ int h[128], cur[128];
  __shared__ int w0tot;
  int bin = blockIdx.x;
  int r0 = cbase_d[bin], r1 = cbase_d[bin + 1];
  int t = threadIdx.x;
  if (t < 128) h[t] = 0;
  __syncthreads();
  for (int i = r0 + t; i < r1; i += 256) atomicAdd(&h[recs_d[i].x >> 17], 1);
  __syncthreads();
  int v = 0, x = 0;
  if (t < 128) {
    v = h[t];
    x = v;
#pragma unroll
    for (int d = 1; d < 64; d <<= 1) { int tt = __shfl_up(x, d); if ((t & 63) >= d) x += tt; }
    if (t == 63) w0tot = x;
  }
  __syncthreads();
  if (t < 128) {
    int excl = x - v + (t >= 64 ? w0tot : 0);
    int node = bin * 128 + t;
    if (node < N) {
      offs[node] = r0 + excl;
      int d = v < 1 ? 1 : v;
      nd[node] = (float)(1.0 / sqrt((double)d));
    }
    cur[t] = r0 + excl;
  }
  __syncthreads();
  for (int i = r0 + t; i < r1; i += 256) {
    int2 rc = recs_d[i];
    int p = atomicAdd(&cur[rc.x >> 17], 1);
    esw[p] = int2{rc.x & 0x1ffff, rc.y};
  }
  // ---- src side: out-degree histogram -> ns ----
  __syncthreads();
  if (t < 128) h[t] = 0;
  __syncthreads();
  int s0 = cbase_s[bin], s1 = cbase_s[bin + 1];
  for (int i = s0 + t; i < s1; i += 256) atomicAdd(&h[recs_s[i] & 127], 1);
  __syncthreads();
  if (t < 128) {
    int node = bin * 128 + t;
    if (node < N) {
      int d = h[t] < 1 ? 1 : h[t];
      ns[node] = (float)(1.0 / sqrt((double)d));
    }
  }
}

// ---------------- merged W split: W1 and W2 -> transposed bf16 hi/lo planes ----------------
__global__ void k_wsplit2(const float* __restrict__ W1, short* __restrict__ w1h,
                          short* __restrict__ w1l, const float* __restrict__ W2,
                          short* __restrict__ w2h, short* __restrict__ w2l) {
  int t = blockIdx.x * blockDim.x + threadIdx.x;
  if (t < D0 * D1) {
    int k = t / D1, n = t % D1;
    float f = W1[t];
    unsigned short h = f2bf(f);
    w1h[(size_t)n * D0 + k] = (short)h;
    w1l[(size_t)n * D0 + k] = (short)f2bf(f - bf2f(h));
  } else if (t < D0 * D1 + D1 * D2) {
    int i = t - D0 * D1;
    int k = i / D2, n = i % D2;
    float f = W2[i];
    unsigned short h = f2bf(f);
    w2h[(size_t)n * D1 + k] = (short)h;
    w2l[(size_t)n * D1 + k] = (short)f2bf(f - bf2f(h));
  }
}

// ---------------- MFMA GEMM: C[M,N] = (A * ns[:,None]) @ W ----------------
template <int K, int N, int WR, int WC>
__launch_bounds__(256, 2)
__global__ void k_gemm_mfma(const float* __restrict__ A, const float* __restrict__ ns,
                            const short* __restrict__ Wth, const short* __restrict__ Wtl,
                            float* __restrict__ C, int M) {
  constexpr int MR = 128 / WR / 16;
  constexpr int NC = N / WC / 16;
  __shared__ short8 Ah[4 * 128], Al[4 * 128];
  __shared__ short8 Bh[4 * N], Bl[4 * N];
  const int t = threadIdx.x;
  const int block_row = blockIdx.x * 128;
  const int lane = t & 63, wid = t >> 6;
  const int wr = wid / WC, wc = wid % WC;
  const int rowbase = wr * (128 / WR), colbase = wc * (N / WC);
  const int c = lane >> 4, lr = lane & 15;
  f32x4 acc[MR][NC] = {};
  const int r = t & 127;
  const int grow = block_row + r;
  float nsv = 0.f;
  if (t < 128 && grow < M) nsv = ns[grow];

  for (int k0 = 0; k0 < K; k0 += 32) {
    if (t < 128) {
      f32x4 v[8];
      if (grow < M) {
        const f32x4* ap = (const f32x4*)(A + (size_t)grow * K + k0);
#pragma unroll
        for (int i = 0; i < 8; ++i) v[i] = ap[i] * nsv;
      } else {
#pragma unroll
        for (int i = 0; i < 8; ++i) v[i] = f32x4{0.f, 0.f, 0.f, 0.f};
      }
#pragma unroll
      for (int cc = 0; cc < 4; ++cc) {
        short8 hi, lo;
#pragma unroll
        for (int i = 0; i < 8; ++i) {
          float f = v[cc * 2 + (i >> 2)][i & 3];
          unsigned short h = f2bf(f);
          hi[i] = (short)h;
          lo[i] = (short)f2bf(f - bf2f(h));
        }
        Ah[cc * 128 + r] = hi;
        Al[cc * 128 + r] = lo;
      }
    } else {
      const int tt = t - 128;
#pragma unroll
      for (int id = tt; id < N * 4; id += 128) {
        int col = id & (N - 1);
        int cb = id / N;
        Bh[cb * N + col] = *(const short8*)(Wth + (size_t)col * K + k0 + cb * 8);
        Bl[cb * N + col] = *(const short8*)(Wtl + (size_t)col * K + k0 + cb * 8);
      }
    }
    __syncthreads();
    short8 ah[MR], al[MR], bh[NC], bl[NC];
#pragma unroll
    for (int m = 0; m < MR; ++m) {
      int row = rowbase + m * 16 + lr;
      ah[m] = Ah[c * 128 + row];
      al[m] = Al[c * 128 + row];
    }
#pragma unroll
    for (int n = 0; n < NC; ++n) {
      int col = colbase + n * 16 + lr;
      bh[n] = Bh[c * N + col];
      bl[n] = Bl[c * N + col];
    }
#pragma unroll
    for (int m = 0; m < MR; ++m)
#pragma unroll
      for (int n = 0; n < NC; ++n) {
        acc[m][n] = __builtin_amdgcn_mfma_f32_16x16x32_bf16(ah[m], bh[n], acc[m][n], 0, 0, 0);
        acc[m][n] = __builtin_amdgcn_mfma_f32_16x16x32_bf16(ah[m], bl[n], acc[m][n], 0, 0, 0);
        acc[m][n] = __builtin_amdgcn_mfma_f32_16x16x32_bf16(al[m], bh[n], acc[m][n], 0, 0, 0);
      }
    __syncthreads();
  }
#pragma unroll
  for (int m = 0; m < MR; ++m) {
#pragma unroll
    for (int j = 0; j < 4; ++j) {
      int row = block_row + rowbase + m * 16 + (lane >> 4) * 4 + j;
      if (row < M) {
#pragma unroll
        for (int n = 0; n < NC; ++n)
          C[(size_t)row * N + colbase + n * 16 + lr] = acc[m][n][j];
      }
    }
  }
}

// ---------------- XCD-sliced agg128: z1[n, sl*32..sl*32+31] per block ----------------
// Slice bound to XCD pair via bid&7 (round-robin dispatch): each XCD's L2 only
// streams 12.8MB of h1 instead of 51MB. Block = 16 nodes x 1 slice; wave = 4
// nodes pipelined; 2 edges per wave-load (32 lanes x 4B = 128B row-slice).
__global__ void k_agg128s(const float* __restrict__ h1, const int* __restrict__ offs,
                          const int2* __restrict__ esw, const float* __restrict__ nd,
                          const float* __restrict__ b1, float* __restrict__ z1, int M) {
  const int lane = threadIdx.x & 63, wid = threadIdx.x >> 6;
  const int bid = blockIdx.x;
  const int sl = (bid & 7) >> 1;                  // slice 0..3 <- XCD pair
  const int ng = ((bid >> 3) << 1) | (bid & 1);   // bijective nodegroup
  const int nb0 = ng * 16 + wid * 4;
  const int p = lane & 31, hi = lane >> 5;
  const int feat = sl * 32 + p;
  float bv = b1[feat];
  int ov = offs[min(nb0 + min(lane, 5), M)];
  int S0[4], S1[4];
#pragma unroll
  for (int q = 0; q < 4; ++q) { S0[q] = rdlane_i(ov, q); S1[q] = rdlane_i(ov, q + 1); }
  int2 ecur{0, 0};
  { int kk = S0[0] + lane; if (kk < S1[0]) ecur = esw[kk]; }
#pragma unroll
  for (int q = 0; q < 4; ++q) {
    const int node = nb0 + q;
    int2 enxt{0, 0};
    if (q < 3) { int kk = S0[q + 1] + lane; if (kk < S1[q + 1]) enxt = esw[kk]; }
    if (node < M) {
      const int s0 = S0[q], s1 = S1[q];
      float acc = 0.f;
      int2 e = ecur;
      for (int bb = s0; bb < s1; bb += 64) {
        if (bb != s0) { int kk = bb + lane; e = (kk < s1) ? esw[kk] : int2{0, 0}; }
        int sidx = e.x;
        float wt = __builtin_bit_cast(float, e.y);
        int cnt = min(64, s1 - bb);
        for (int jj = 0; jj < cnt; jj += 16) {
          float v[8];
#pragma unroll
          for (int u = 0; u < 8; ++u) {
            int r0 = rdlane_i(sidx, jj + 2 * u);
            int r1 = rdlane_i(sidx, jj + 2 * u + 1);
            int s = hi ? r1 : r0;
            v[u] = h1[(size_t)(unsigned)s * 128 + feat];
          }
          __builtin_amdgcn_sched_barrier(0);  // keep all 8 gathers in flight
#pragma unroll
          for (int u = 0; u < 8; ++u) {
            float w0 = rdlane_f(wt, jj + 2 * u);
            float w1 = rdlane_f(wt, jj + 2 * u + 1);
            acc += v[u] * (hi ? w1 : w0);
          }
        }
      }
      acc += __shfl_xor(acc, 32);
      if (hi == 0) {
        float z = fmaxf(acc * nd[node] + bv, 0.f);
        z1[(size_t)node * 128 + feat] = z;  // unscaled; gemm2 applies ns
      }
    }
    ecur = enxt;
  }
}

// ---------------- agg64+matvec: dwordx4 gather, 4 edges per wave-load ----------------
__global__ void k_agg64mv(const float* __restrict__ h, const int* __restrict__ offs,
                          const int2* __restrict__ esw, const float* __restrict__ nd,
                          const float* __restrict__ b2, const float* __restrict__ W3,
                          const float* __restrict__ ns, float* __restrict__ h3, int M) {
  const int lane = threadIdx.x & 63;
  const int wave = blockIdx.x * (blockDim.x >> 6) + (threadIdx.x >> 6);
  const int nb0 = wave * 4;
  if (nb0 >= M) return;
  const f32x4* hp4 = (const f32x4*)h;
  const int p = lane & 15;
  const int q4 = lane >> 4;
  const bool qb0 = q4 & 1, qb1 = q4 & 2;
  f32x4 bv = ((const f32x4*)b2)[p];
  f32x4 w3v = ((const f32x4*)W3)[p];
  int ov = offs[min(nb0 + min(lane, 5), M)];
  int S0[4], S1[4];
#pragma unroll
  for (int q = 0; q < 4; ++q) { S0[q] = rdlane_i(ov, q); S1[q] = rdlane_i(ov, q + 1); }
  int2 ecur{0, 0};
  { int kk = S0[0] + lane; if (kk < S1[0]) ecur = esw[kk]; }
#pragma unroll
  for (int q = 0; q < 4; ++q) {
    const int node = nb0 + q;
    int2 enxt{0, 0};
    if (q < 3) { int kk = S0[q + 1] + lane; if (kk < S1[q + 1]) enxt = esw[kk]; }
    if (node < M) {
      const int s0 = S0[q], s1 = S1[q];
      f32x4 acc = {};
      int2 e = ecur;
      for (int bb = s0; bb < s1; bb += 64) {
        if (bb != s0) { int kk = bb + lane; e = (kk < s1) ? esw[kk] : int2{0, 0}; }
        int sidx = e.x;
        float wt = __builtin_bit_cast(float, e.y);
        int cnt = min(64, s1 - bb);
        for (int jj = 0; jj < cnt; jj += 32) {
          f32x4 v[8];
#pragma unroll
          for (int u = 0; u < 8; ++u) {
            int ei = jj + 4 * u;
            int r0 = rdlane_i(sidx, ei), r1 = rdlane_i(sidx, ei + 1);
            int r2 = rdlane_i(sidx, ei + 2), r3 = rdlane_i(sidx, ei + 3);
            int c01 = qb0 ? r1 : r0;
            int c23 = qb0 ? r3 : r2;
            int s = qb1 ? c23 : c01;
            v[u] = hp4[(size_t)(unsigned)s * 16 + p];
          }
          __builtin_amdgcn_sched_barrier(0);
#pragma unroll
          for (int u = 0; u < 8; ++u) {
            int ei = jj + 4 * u;
            float w0 = rdlane_f(wt, ei), w1 = rdlane_f(wt, ei + 1);
            float w2 = rdlane_f(wt, ei + 2), w3s = rdlane_f(wt, ei + 3);
            float c01 = qb0 ? w1 : w0;
            float c23 = qb0 ? w3s : w2;
            float wu = qb1 ? c23 : c01;
            acc[0] += v[u][0] * wu;
            acc[1] += v[u][1] * wu;
            acc[2] += v[u][2] * wu;
            acc[3] += v[u][3] * wu;
          }
        }
      }
#pragma unroll
      for (int i = 0; i < 4; ++i) {
        acc[i] += __shfl_xor(acc[i], 16);
        acc[i] += __shfl_xor(acc[i], 32);
      }
      float ndv = nd[node];
      float dp = 0.f;
#pragma unroll
      for (int i = 0; i < 4; ++i) dp += fmaxf(acc[i] * ndv + bv[i], 0.f) * w3v[i];
#pragma unroll
      for (int d = 8; d; d >>= 1) dp += __shfl_xor(dp, d);
      if (lane == 0) h3[node] = dp * ns[node];
    }
    ecur = enxt;
  }
}

// ---------------- final scalar aggregation: 16-deep batched gathers ----------------
__launch_bounds__(256)
__global__ void k_aggfin(const float* __restrict__ h3, const int* __restrict__ offs,
                         const int2* __restrict__ esw, const float* __restrict__ nd,
                         const float* __restrict__ b3, float* __restrict__ out, int M) {
  int i = blockIdx.x * blockDim.x + threadIdx.x;
  if (i >= M) return;
  int s0 = offs[i], s1 = offs[i + 1];
  float acc = 0.f;
  for (int k0 = s0; k0 < s1; k0 += 16) {
    int nn = min(16, s1 - k0);
    int2 e[16];
    float hv[16];
#pragma unroll
    for (int u = 0; u < 16; ++u) e[u] = esw[k0 + min(u, nn - 1)];
#pragma unroll
    for (int u = 0; u < 16; ++u) hv[u] = h3[e[u].x];
    __builtin_amdgcn_sched_barrier(0);
#pragma unroll
    for (int u = 0; u < 16; ++u)
      if (u < nn) acc += hv[u] * __builtin_bit_cast(float, e[u].y);
  }
  out[i] = acc * nd[i] + b3[0];
}

extern "C" void kernel_launch(void* const* d_in, const int* in_sizes, int n_in,
                              void* d_out, int out_size, void* d_ws, size_t ws_size,
                              hipStream_t stream) {
  const float* b_z = (const float*)d_in[0];
  const int*   src = (const int*)d_in[1];
  const int*   dst = (const int*)d_in[2];
  const float* ew  = (const float*)d_in[3];
  const float* W1  = (const float*)d_in[5];
  const float* b1  = (const float*)d_in[6];
  const float* W2  = (const float*)d_in[7];
  const float* b2  = (const float*)d_in[8];
  const float* W3  = (const float*)d_in[9];
  const float* b3  = (const float*)d_in[10];
  const int N = in_sizes[0] / D0;
  const int E = in_sizes[1];
  float* out = (float*)d_out;

  char* ws = (char*)d_ws;
  size_t off_b = 0;
  auto alloc = [&](size_t bytes) -> void* {
    void* p = ws + off_b;
    off_b += (bytes + 255) & ~(size_t)255;
    return p;
  };
  const int nbk = (E + EBLK - 1) / EBLK;
  int*   bc_s    = (int*)alloc((size_t)nbk * NB * 4);
  int*   bc_d    = (int*)alloc((size_t)nbk * NB * 4);
  int*   bt_s    = (int*)alloc((size_t)NB * 4);
  int*   bt_d    = (int*)alloc((size_t)NB * 4);
  int*   cbase_s = (int*)alloc((size_t)(NB + 1) * 4);
  int*   cbase_d = (int*)alloc((size_t)(NB + 1) * 4);
  int*   offs    = (int*)alloc((size_t)(N + 1) * 4);
  int2*  esw     = (int2*)alloc((size_t)E * 8);
  float* nsrc    = (float*)alloc((size_t)N * 4);
  float* ndst    = (float*)alloc((size_t)N * 4);
  float* h1      = (float*)alloc((size_t)N * D1 * 4);  // 51.2 MB
  float* z1      = (float*)alloc((size_t)N * D1 * 4);  // 51.2 MB
  float* h2      = (float*)alloc((size_t)N * D2 * 4);  // 25.6 MB
  float* h3      = (float*)alloc((size_t)N * 4);
  short* wt1h    = (short*)alloc((size_t)D0 * D1 * 2);
  short* wt1l    = (short*)alloc((size_t)D0 * D1 * 2);
  short* wt2h    = (short*)alloc((size_t)D1 * D2 * 2);
  short* wt2l    = (short*)alloc((size_t)D1 * D2 * 2);
  // partition records alias h1/z1 (dead before GEMM1/agg128s write them)
  int2*  recs_d = (int2*)h1;   // E*8 = 12.8 MB
  int*   recs_s = (int*)z1;    // E*4 = 6.4 MB

  // --- CSR build (atomic-free, fully parallel) ---
  k_chist2<<<nbk, 256, 0, stream>>>(src, dst, bc_s, bc_d, E);
  k_binscan<<<dim3(NB / 16, 2), 256, 0, stream>>>(bc_s, bt_s, bc_d, bt_d, nbk);
  k_btscan<<<2, 1024, 0, stream>>>(bt_s, cbase_s, bt_d, cbase_d, &offs[N], E);
  k_cpart2<<<nbk, 256, 0, stream>>>(src, dst, ew, bc_s, cbase_s, bc_d, cbase_d,
                                    recs_s, recs_d, E);
  k_finecomb<<<NB, 256, 0, stream>>>(recs_d, cbase_d, recs_s, cbase_s, esw, offs,
                                     ndst, nsrc, N);
  k_wsplit2<<<(D0 * D1 + D1 * D2 + 255) / 256, 256, 0, stream>>>(W1, wt1h, wt1l,
                                                                 W2, wt2h, wt2l);

  // layer 1: 256 -> 128 (MFMA)
  k_gemm_mfma<D0, D1, 2, 2><<<(N + 127) / 128, 256, 0, stream>>>(b_z, nsrc, wt1h, wt1l, h1, N);
  // layer-1 aggregation, XCD-feature-sliced (writes z1, unscaled)
  int NG = (N + 15) / 16;
  if (NG & 1) ++NG;  // bijective swizzle needs even NG
  k_agg128s<<<NG * 4, 256, 0, stream>>>(h1, offs, esw, ndst, b1, z1, N);
  // layer 2: 128 -> 64 (MFMA, applies ns)
  k_gemm_mfma<D1, D2, 4, 1><<<(N + 127) / 128, 256, 0, stream>>>(z1, nsrc, wt2h, wt2l, h2, N);
  // layer-2 agg fused with layer-3 projection (64->1 matvec)
  k_agg64mv<<<(N + 15) / 16, 256, 0, stream>>>(h2, offs, esw, ndst, b2, W3, nsrc, h3, N);
  // final scalar aggregation
  k_aggfin<<<(N + 255) / 256, 256, 0, stream>>>(h3, offs, esw, ndst, b3, out, N);
}

// Round 12
// 334.102 us; speedup vs baseline: 1.3061x; 1.3061x over previous
//
#include <hip/hip_runtime.h>

// GCN decoder. Atomic-free CSR build (two-level counting sort) ->
// GEMM1(MFMA bf16-split) -> agg128 FUSED with GEMM2 (LDS mini-GEMM epilogue) ->
// agg64+matvec(W3) -> final scalar agg.
// Round 12: REVERT r11 slicing; LDS-staged edge meta (ds_read_b64 broadcast
// replaces readlane/cndmask decode) in both gather kernels; EBLK 2048.

constexpr int D0 = 256, D1 = 128, D2 = 64;
constexpr int NB = 1024;   // coarse bins
constexpr int BSH = 7;     // bin = key >> 7 (128 nodes per bin)
constexpr int EBLK = 2048; // edges per block in hist/partition kernels

typedef __attribute__((ext_vector_type(2))) float f32x2;
typedef __attribute__((ext_vector_type(4))) float f32x4;
typedef __attribute__((ext_vector_type(8))) short short8;

__device__ inline unsigned short f2bf(float f) {
  unsigned u = __builtin_bit_cast(unsigned, f);
  u += 0x7fffu + ((u >> 16) & 1u);
  return (unsigned short)(u >> 16);
}
__device__ inline float bf2f(unsigned short h) {
  unsigned u = ((unsigned)h) << 16;
  return __builtin_bit_cast(float, u);
}
__device__ inline int rdlane_i(int v, int l) { return __builtin_amdgcn_readlane(v, l); }

// ---------------- merged coarse histograms: src and dst in one edge pass ----------------
__global__ void k_chist2(const int* __restrict__ src, const int* __restrict__ dst,
                         int* __restrict__ bc_s, int* __restrict__ bc_d, int E) {
  __shared__ int hs[NB], hd[NB];
  for (int i = threadIdx.x; i < NB; i += 256) { hs[i] = 0; hd[i] = 0; }
  __syncthreads();
  int e0 = blockIdx.x * EBLK, e1 = min(e0 + EBLK, E);
  for (int i = e0 + threadIdx.x; i < e1; i += 256) {
    atomicAdd(&hs[src[i] >> BSH], 1);
    atomicAdd(&hd[dst[i] >> BSH], 1);
  }
  __syncthreads();
  for (int i = threadIdx.x; i < NB; i += 256) {
    bc_s[blockIdx.x * NB + i] = hs[i];
    bc_d[blockIdx.x * NB + i] = hd[i];
  }
}

// ---------------- coalesced column scan: block = 16 consecutive bins ----------------
__global__ void k_binscan(int* __restrict__ bc_s, int* __restrict__ bt_s,
                          int* __restrict__ bc_d, int* __restrict__ bt_d, int nbk) {
  __shared__ int part[16][17];
  int* bc = blockIdx.y ? bc_d : bc_s;
  int* bt = blockIdx.y ? bt_d : bt_s;
  const int j = threadIdx.x & 15;
  const int c = threadIdx.x >> 4;
  const int bin = blockIdx.x * 16 + j;
  const int chunk = (nbk + 15) / 16;
  const int r0 = c * chunk, r1 = min(r0 + chunk, nbk);
  int s = 0;
  for (int b = r0; b < r1; ++b) s += bc[b * NB + bin];
  part[c][j] = s;
  __syncthreads();
  int pre = 0;
  for (int q = 0; q < c; ++q) pre += part[q][j];
  int run = pre;
  for (int b = r0; b < r1; ++b) {
    int v = bc[b * NB + bin];
    bc[b * NB + bin] = run;
    run += v;
  }
  if (c == 15) bt[bin] = run;
}

// ---------------- scan of 1024 bin totals (block 0: src, block 1: dst) ----------------
__global__ void k_btscan(const int* __restrict__ bt_s, int* __restrict__ cbase_s,
                         const int* __restrict__ bt_d, int* __restrict__ cbase_d,
                         int* __restrict__ offs_end, int E) {
  __shared__ int wsum[16];
  const int* bt = blockIdx.x ? bt_d : bt_s;
  int* cbase = blockIdx.x ? cbase_d : cbase_s;
  int tid = threadIdx.x, lane = tid & 63, wid = tid >> 6;
  int v = bt[tid];
  int x = v;
#pragma unroll
  for (int d = 1; d < 64; d <<= 1) { int t = __shfl_up(x, d); if (lane >= d) x += t; }
  if (lane == 63) wsum[wid] = x;
  __syncthreads();
  if (wid == 0 && lane < 16) {
    int s = wsum[lane];
#pragma unroll
    for (int d = 1; d < 16; d <<= 1) { int t = __shfl_up(s, d, 16); if (lane >= d) s += t; }
    wsum[lane] = s;
  }
  __syncthreads();
  int excl = x - v + (wid ? wsum[wid - 1] : 0);
  cbase[tid] = excl;
  if (tid == NB - 1) cbase[NB] = E;
  if (blockIdx.x == 1 && tid == 0) *offs_end = E;
}

// ---------------- merged coarse partition: one edge pass, both sides ----------------
__global__ void k_cpart2(const int* __restrict__ src, const int* __restrict__ dst,
                         const float* __restrict__ ew,
                         const int* __restrict__ bc_s, const int* __restrict__ cbase_s,
                         const int* __restrict__ bc_d, const int* __restrict__ cbase_d,
                         int* __restrict__ recs_s, int2* __restrict__ recs_d, int E) {
  __shared__ int cs[NB], cd[NB];
  for (int i = threadIdx.x; i < NB; i += 256) {
    cs[i] = cbase_s[i] + bc_s[blockIdx.x * NB + i];
    cd[i] = cbase_d[i] + bc_d[blockIdx.x * NB + i];
  }
  __syncthreads();
  int e0 = blockIdx.x * EBLK, e1 = min(e0 + EBLK, E);
  for (int i = e0 + threadIdx.x; i < e1; i += 256) {
    int s = src[i], d = dst[i];
    int ps = atomicAdd(&cs[s >> BSH], 1);
    recs_s[ps] = s;
    int pd = atomicAdd(&cd[d >> BSH], 1);
    recs_d[pd] = int2{s | ((d & 127) << 17), __builtin_bit_cast(int, ew[i])};
  }
}

// ---------------- merged fine pass: dst CSR (offs, nd, esw) + src hist (ns) ----------------
__global__ void k_finecomb(const int2* __restrict__ recs_d, const int* __restrict__ cbase_d,
                           const int* __restrict__ recs_s, const int* __restrict__ cbase_s,
                           int2* __restrict__ esw, int* __restrict__ offs,
                           float* __restrict__ nd, float* __restrict__ ns, int N) {
  __shared__ int h[128], cur[128];
  __shared__ int w0tot;
  int bin = blockIdx.x;
  int r0 = cbase_d[bin], r1 = cbase_d[bin + 1];
  int t = threadIdx.x;
  if (t < 128) h[t] = 0;
  __syncthreads();
  for (int i = r0 + t; i < r1; i += 256) atomicAdd(&h[recs_d[i].x >> 17], 1);
  __syncthreads();
  int v = 0, x = 0;
  if (t < 128) {
    v = h[t];
    x = v;
#pragma unroll
    for (int d = 1; d < 64; d <<= 1) { int tt = __shfl_up(x, d); if ((t & 63) >= d) x += tt; }
    if (t == 63) w0tot = x;
  }
  __syncthreads();
  if (t < 128) {
    int excl = x - v + (t >= 64 ? w0tot : 0);
    int node = bin * 128 + t;
    if (node < N) {
      offs[node] = r0 + excl;
      int d = v < 1 ? 1 : v;
      nd[node] = (float)(1.0 / sqrt((double)d));
    }
    cur[t] = r0 + excl;
  }
  __syncthreads();
  for (int i = r0 + t; i < r1; i += 256) {
    int2 rc = recs_d[i];
    int p = atomicAdd(&cur[rc.x >> 17], 1);
    esw[p] = int2{rc.x & 0x1ffff, rc.y};
  }
  // ---- src side: out-degree histogram -> ns ----
  __syncthreads();
  if (t < 128) h[t] = 0;
  __syncthreads();
  int s0 = cbase_s[bin], s1 = cbase_s[bin + 1];
  for (int i = s0 + t; i < s1; i += 256) atomicAdd(&h[recs_s[i] & 127], 1);
  __syncthreads();
  if (t < 128) {
    int node = bin * 128 + t;
    if (node < N) {
      int d = h[t] < 1 ? 1 : h[t];
      ns[node] = (float)(1.0 / sqrt((double)d));
    }
  }
}

// ---------------- merged W split: W1 and W2 -> transposed bf16 hi/lo planes ----------------
__global__ void k_wsplit2(const float* __restrict__ W1, short* __restrict__ w1h,
                          short* __restrict__ w1l, const float* __restrict__ W2,
                          short* __restrict__ w2h, short* __restrict__ w2l) {
  int t = blockIdx.x * blockDim.x + threadIdx.x;
  if (t < D0 * D1) {
    int k = t / D1, n = t % D1;
    float f = W1[t];
    unsigned short h = f2bf(f);
    w1h[(size_t)n * D0 + k] = (short)h;
    w1l[(size_t)n * D0 + k] = (short)f2bf(f - bf2f(h));
  } else if (t < D0 * D1 + D1 * D2) {
    int i = t - D0 * D1;
    int k = i / D2, n = i % D2;
    float f = W2[i];
    unsigned short h = f2bf(f);
    w2h[(size_t)n * D1 + k] = (short)h;
    w2l[(size_t)n * D1 + k] = (short)f2bf(f - bf2f(h));
  }
}

// ---------------- MFMA GEMM (layer 1): C[M,N] = (A * ns[:,None]) @ W ----------------
template <int K, int N, int WR, int WC>
__launch_bounds__(256, 2)
__global__ void k_gemm_mfma(const float* __restrict__ A, const float* __restrict__ ns,
                            const short* __restrict__ Wth, const short* __restrict__ Wtl,
                            float* __restrict__ C, int M) {
  constexpr int MR = 128 / WR / 16;
  constexpr int NC = N / WC / 16;
  __shared__ short8 Ah[4 * 128], Al[4 * 128];
  __shared__ short8 Bh[4 * N], Bl[4 * N];
  const int t = threadIdx.x;
  const int block_row = blockIdx.x * 128;
  const int lane = t & 63, wid = t >> 6;
  const int wr = wid / WC, wc = wid % WC;
  const int rowbase = wr * (128 / WR), colbase = wc * (N / WC);
  const int c = lane >> 4, lr = lane & 15;
  f32x4 acc[MR][NC] = {};
  const int r = t & 127;
  const int grow = block_row + r;
  float nsv = 0.f;
  if (t < 128 && grow < M) nsv = ns[grow];

  for (int k0 = 0; k0 < K; k0 += 32) {
    if (t < 128) {
      f32x4 v[8];
      if (grow < M) {
        const f32x4* ap = (const f32x4*)(A + (size_t)grow * K + k0);
#pragma unroll
        for (int i = 0; i < 8; ++i) v[i] = ap[i] * nsv;
      } else {
#pragma unroll
        for (int i = 0; i < 8; ++i) v[i] = f32x4{0.f, 0.f, 0.f, 0.f};
      }
#pragma unroll
      for (int cc = 0; cc < 4; ++cc) {
        short8 hi, lo;
#pragma unroll
        for (int i = 0; i < 8; ++i) {
          float f = v[cc * 2 + (i >> 2)][i & 3];
          unsigned short h = f2bf(f);
          hi[i] = (short)h;
          lo[i] = (short)f2bf(f - bf2f(h));
        }
        Ah[cc * 128 + r] = hi;
        Al[cc * 128 + r] = lo;
      }
    } else {
      const int tt = t - 128;
#pragma unroll
      for (int id = tt; id < N * 4; id += 128) {
        int col = id & (N - 1);
        int cb = id / N;
        Bh[cb * N + col] = *(const short8*)(Wth + (size_t)col * K + k0 + cb * 8);
        Bl[cb * N + col] = *(const short8*)(Wtl + (size_t)col * K + k0 + cb * 8);
      }
    }
    __syncthreads();
    short8 ah[MR], al[MR], bh[NC], bl[NC];
#pragma unroll
    for (int m = 0; m < MR; ++m) {
      int row = rowbase + m * 16 + lr;
      ah[m] = Ah[c * 128 + row];
      al[m] = Al[c * 128 + row];
    }
#pragma unroll
    for (int n = 0; n < NC; ++n) {
      int col = colbase + n * 16 + lr;
      bh[n] = Bh[c * N + col];
      bl[n] = Bl[c * N + col];
    }
#pragma unroll
    for (int m = 0; m < MR; ++m)
#pragma unroll
      for (int n = 0; n < NC; ++n) {
        acc[m][n] = __builtin_amdgcn_mfma_f32_16x16x32_bf16(ah[m], bh[n], acc[m][n], 0, 0, 0);
        acc[m][n] = __builtin_amdgcn_mfma_f32_16x16x32_bf16(ah[m], bl[n], acc[m][n], 0, 0, 0);
        acc[m][n] = __builtin_amdgcn_mfma_f32_16x16x32_bf16(al[m], bh[n], acc[m][n], 0, 0, 0);
      }
    __syncthreads();
  }
#pragma unroll
  for (int m = 0; m < MR; ++m) {
#pragma unroll
    for (int j = 0; j < 4; ++j) {
      int row = block_row + rowbase + m * 16 + (lane >> 4) * 4 + j;
      if (row < M) {
#pragma unroll
        for (int n = 0; n < NC; ++n)
          C[(size_t)row * N + colbase + n * 16 + lr] = acc[m][n][j];
      }
    }
  }
}

// ---------------- FUSED agg128 + GEMM2: LDS-staged edge meta, 2 edges/wave-load ----------------
// Half-wave per edge: p=lane&31 covers features 4p..4p+3 (f32x4); halves combined
// via shfl_xor(32). Edge meta staged in per-wave LDS; ds_read_b64 broadcast gives
// index+weight with no readlane/cndmask.
__launch_bounds__(256, 4)
__global__ void k_agg128f(const float* __restrict__ h, const int* __restrict__ offs,
                          const int2* __restrict__ esw, const float* __restrict__ nd,
                          const float* __restrict__ b1v, const float* __restrict__ ns,
                          const short* __restrict__ w2h, const short* __restrict__ w2l,
                          float* __restrict__ h2, int M) {
  __shared__ unsigned Ah32[16 * 64], Al32[16 * 64];
  __shared__ int2 emeta[4][64];
  const int t = threadIdx.x, lane = t & 63, wid = t >> 6;
  const int base = blockIdx.x * 16;
  const int nb0 = base + wid * 4;
  const f32x4* hp4 = (const f32x4*)h;
  const int p = lane & 31;
  const int hi = lane >> 5;
  f32x4 bv = ((const f32x4*)b1v)[p];
  int ov = offs[min(nb0 + min(lane, 5), M)];
  int S0[4], S1[4];
#pragma unroll
  for (int q = 0; q < 4; ++q) { S0[q] = rdlane_i(ov, q); S1[q] = rdlane_i(ov, q + 1); }
  int2 ecur{0, 0};
  { int kk = S0[0] + lane; if (kk < S1[0]) ecur = esw[kk]; }
#pragma unroll
  for (int q = 0; q < 4; ++q) {
    const int row = wid * 4 + q;
    const int node = nb0 + q;
    int2 enxt{0, 0};
    if (q < 3) { int kk = S0[q + 1] + lane; if (kk < S1[q + 1]) enxt = esw[kk]; }
    unsigned hw0 = 0, hw1 = 0, lw0 = 0, lw1 = 0;
    if (node < M) {
      const int s0 = S0[q], s1 = S1[q];
      f32x4 acc = {};
      int2 e = ecur;
      for (int bb = s0; bb < s1; bb += 64) {
        if (bb != s0) { int kk = bb + lane; e = (kk < s1) ? esw[kk] : int2{0, 0}; }
        emeta[wid][lane] = e;  // per-wave buffer; in-order LDS pipe, no barrier
        int cnt = min(64, s1 - bb);
        for (int jj = 0; jj < cnt; jj += 16) {
          int2 em[8];
          f32x4 v[8];
#pragma unroll
          for (int u = 0; u < 8; ++u) em[u] = emeta[wid][jj + 2 * u + hi];
#pragma unroll
          for (int u = 0; u < 8; ++u)
            v[u] = hp4[(size_t)(unsigned)em[u].x * 32 + p];
          __builtin_amdgcn_sched_barrier(0);  // keep all 8 x 1KB gathers in flight
#pragma unroll
          for (int u = 0; u < 8; ++u) {
            float wu = __builtin_bit_cast(float, em[u].y);
            acc[0] += v[u][0] * wu;
            acc[1] += v[u][1] * wu;
            acc[2] += v[u][2] * wu;
            acc[3] += v[u][3] * wu;
          }
        }
      }
      f32x4 o;
#pragma unroll
      for (int i = 0; i < 4; ++i) o[i] = acc[i] + __shfl_xor(acc[i], 32);
      float ndv = nd[node], nsv = ns[node];
      float z[4];
#pragma unroll
      for (int i = 0; i < 4; ++i) z[i] = fmaxf(o[i] * ndv + bv[i], 0.f) * nsv;
      unsigned short h0 = f2bf(z[0]), h1b = f2bf(z[1]), h2b = f2bf(z[2]), h3b = f2bf(z[3]);
      hw0 = (unsigned)h0 | ((unsigned)h1b << 16);
      hw1 = (unsigned)h2b | ((unsigned)h3b << 16);
      lw0 = (unsigned)f2bf(z[0] - bf2f(h0)) | ((unsigned)f2bf(z[1] - bf2f(h1b)) << 16);
      lw1 = (unsigned)f2bf(z[2] - bf2f(h2b)) | ((unsigned)f2bf(z[3] - bf2f(h3b)) << 16);
    }
    if (lane < 32) {
      int widx = (2 * p) ^ ((row & 7) << 2);  // XOR swizzle, preserves word pairing
      *(uint2*)&Ah32[row * 64 + widx] = uint2{hw0, hw1};
      *(uint2*)&Al32[row * 64 + widx] = uint2{lw0, lw1};
    }
    ecur = enxt;
  }
  __syncthreads();
  // B-frags for this wave's 16-col tile of W2 ([64][128] bf16 planes)
  const int colB = wid * 16 + (lane & 15);
  const int koff = (lane >> 4) * 8;
  short8 bh[4], bl[4];
#pragma unroll
  for (int ks = 0; ks < 4; ++ks) {
    bh[ks] = *(const short8*)(w2h + (size_t)colB * 128 + ks * 32 + koff);
    bl[ks] = *(const short8*)(w2l + (size_t)colB * 128 + ks * 32 + koff);
  }
  const int arow = lane & 15, ac = lane >> 4;
  f32x4 acc = {};
#pragma unroll
  for (int ks = 0; ks < 4; ++ks) {
    int bidx = arow * 64 + ((ks * 16 + ac * 4) ^ ((arow & 7) << 2));
    short8 ah = *(const short8*)(Ah32 + bidx);
    short8 al = *(const short8*)(Al32 + bidx);
    acc = __builtin_amdgcn_mfma_f32_16x16x32_bf16(ah, bh[ks], acc, 0, 0, 0);
    acc = __builtin_amdgcn_mfma_f32_16x16x32_bf16(ah, bl[ks], acc, 0, 0, 0);
    acc = __builtin_amdgcn_mfma_f32_16x16x32_bf16(al, bh[ks], acc, 0, 0, 0);
  }
  const int crow = (lane >> 4) * 4;
  const int col = wid * 16 + (lane & 15);
#pragma unroll
  for (int j = 0; j < 4; ++j) {
    int node = base + crow + j;
    if (node < M) h2[(size_t)node * 64 + col] = acc[j];
  }
}

// ---------------- agg64+matvec: LDS-staged edge meta, 4 edges/wave-load ----------------
__global__ void k_agg64mv(const float* __restrict__ h, const int* __restrict__ offs,
                          const int2* __restrict__ esw, const float* __restrict__ nd,
                          const float* __restrict__ b2, const float* __restrict__ W3,
                          const float* __restrict__ ns, float* __restrict__ h3, int M) {
  __shared__ int2 emeta[4][64];
  const int lane = threadIdx.x & 63, wid = threadIdx.x >> 6;
  const int wave = blockIdx.x * (blockDim.x >> 6) + wid;
  const int nb0 = wave * 4;
  if (nb0 >= M) return;
  const f32x4* hp4 = (const f32x4*)h;
  const int p = lane & 15;
  const int q4 = lane >> 4;
  f32x4 bv = ((const f32x4*)b2)[p];
  f32x4 w3v = ((const f32x4*)W3)[p];
  int ov = offs[min(nb0 + min(lane, 5), M)];
  int S0[4], S1[4];
#pragma unroll
  for (int q = 0; q < 4; ++q) { S0[q] = rdlane_i(ov, q); S1[q] = rdlane_i(ov, q + 1); }
  int2 ecur{0, 0};
  { int kk = S0[0] + lane; if (kk < S1[0]) ecur = esw[kk]; }
#pragma unroll
  for (int q = 0; q < 4; ++q) {
    const int node = nb0 + q;
    int2 enxt{0, 0};
    if (q < 3) { int kk = S0[q + 1] + lane; if (kk < S1[q + 1]) enxt = esw[kk]; }
    if (node < M) {
      const int s0 = S0[q], s1 = S1[q];
      f32x4 acc = {};
      int2 e = ecur;
      for (int bb = s0; bb < s1; bb += 64) {
        if (bb != s0) { int kk = bb + lane; e = (kk < s1) ? esw[kk] : int2{0, 0}; }
        emeta[wid][lane] = e;
        int cnt = min(64, s1 - bb);
        for (int jj = 0; jj < cnt; jj += 32) {
          int2 em[8];
          f32x4 v[8];
#pragma unroll
          for (int u = 0; u < 8; ++u) em[u] = emeta[wid][jj + 4 * u + q4];
#pragma unroll
          for (int u = 0; u < 8; ++u)
            v[u] = hp4[(size_t)(unsigned)em[u].x * 16 + p];
          __builtin_amdgcn_sched_barrier(0);
#pragma unroll
          for (int u = 0; u < 8; ++u) {
            float wu = __builtin_bit_cast(float, em[u].y);
            acc[0] += v[u][0] * wu;
            acc[1] += v[u][1] * wu;
            acc[2] += v[u][2] * wu;
            acc[3] += v[u][3] * wu;
          }
        }
      }
#pragma unroll
      for (int i = 0; i < 4; ++i) {
        acc[i] += __shfl_xor(acc[i], 16);
        acc[i] += __shfl_xor(acc[i], 32);
      }
      float ndv = nd[node];
      float dp = 0.f;
#pragma unroll
      for (int i = 0; i < 4; ++i) dp += fmaxf(acc[i] * ndv + bv[i], 0.f) * w3v[i];
#pragma unroll
      for (int d = 8; d; d >>= 1) dp += __shfl_xor(dp, d);
      if (lane == 0) h3[node] = dp * ns[node];
    }
    ecur = enxt;
  }
}

// ---------------- final scalar aggregation: 16-deep batched gathers ----------------
__launch_bounds__(256)
__global__ void k_aggfin(const float* __restrict__ h3, const int* __restrict__ offs,
                         const int2* __restrict__ esw, const float* __restrict__ nd,
                         const float* __restrict__ b3, float* __restrict__ out, int M) {
  int i = blockIdx.x * blockDim.x + threadIdx.x;
  if (i >= M) return;
  int s0 = offs[i], s1 = offs[i + 1];
  float acc = 0.f;
  for (int k0 = s0; k0 < s1; k0 += 16) {
    int nn = min(16, s1 - k0);
    int2 e[16];
    float hv[16];
#pragma unroll
    for (int u = 0; u < 16; ++u) e[u] = esw[k0 + min(u, nn - 1)];
#pragma unroll
    for (int u = 0; u < 16; ++u) hv[u] = h3[e[u].x];
    __builtin_amdgcn_sched_barrier(0);
#pragma unroll
    for (int u = 0; u < 16; ++u)
      if (u < nn) acc += hv[u] * __builtin_bit_cast(float, e[u].y);
  }
  out[i] = acc * nd[i] + b3[0];
}

extern "C" void kernel_launch(void* const* d_in, const int* in_sizes, int n_in,
                              void* d_out, int out_size, void* d_ws, size_t ws_size,
                              hipStream_t stream) {
  const float* b_z = (const float*)d_in[0];
  const int*   src = (const int*)d_in[1];
  const int*   dst = (const int*)d_in[2];
  const float* ew  = (const float*)d_in[3];
  const float* W1  = (const float*)d_in[5];
  const float* b1  = (const float*)d_in[6];
  const float* W2  = (const float*)d_in[7];
  const float* b2  = (const float*)d_in[8];
  const float* W3  = (const float*)d_in[9];
  const float* b3  = (const float*)d_in[10];
  const int N = in_sizes[0] / D0;
  const int E = in_sizes[1];
  float* out = (float*)d_out;

  char* ws = (char*)d_ws;
  size_t off_b = 0;
  auto alloc = [&](size_t bytes) -> void* {
    void* p = ws + off_b;
    off_b += (bytes + 255) & ~(size_t)255;
    return p;
  };
  const int nbk = (E + EBLK - 1) / EBLK;
  int*   bc_s    = (int*)alloc((size_t)nbk * NB * 4);
  int*   bc_d    = (int*)alloc((size_t)nbk * NB * 4);
  int*   bt_s    = (int*)alloc((size_t)NB * 4);
  int*   bt_d    = (int*)alloc((size_t)NB * 4);
  int*   cbase_s = (int*)alloc((size_t)(NB + 1) * 4);
  int*   cbase_d = (int*)alloc((size_t)(NB + 1) * 4);
  int*   offs    = (int*)alloc((size_t)(N + 1) * 4);
  int2*  esw     = (int2*)alloc((size_t)E * 8);
  float* nsrc    = (float*)alloc((size_t)N * 4);
  float* ndst    = (float*)alloc((size_t)N * 4);
  float* h1      = (float*)alloc((size_t)N * D1 * 4);  // 51.2 MB
  float* h2      = (float*)alloc((size_t)N * D2 * 4);  // 25.6 MB
  float* h3      = (float*)alloc((size_t)N * 4);
  short* wt1h    = (short*)alloc((size_t)D0 * D1 * 2);
  short* wt1l    = (short*)alloc((size_t)D0 * D1 * 2);
  short* wt2h    = (short*)alloc((size_t)D1 * D2 * 2);
  short* wt2l    = (short*)alloc((size_t)D1 * D2 * 2);
  // partition records alias h1 (both dead before GEMM1 writes h1)
  int2*  recs_d = (int2*)h1;                              // E*8 = 12.8 MB
  int*   recs_s = (int*)((char*)h1 + ((size_t)16 << 20)); // E*4 = 6.4 MB @ +16MB

  // --- CSR build (atomic-free, fully parallel) ---
  k_chist2<<<nbk, 256, 0, stream>>>(src, dst, bc_s, bc_d, E);
  k_binscan<<<dim3(NB / 16, 2), 256, 0, stream>>>(bc_s, bt_s, bc_d, bt_d, nbk);
  k_btscan<<<2, 1024, 0, stream>>>(bt_s, cbase_s, bt_d, cbase_d, &offs[N], E);
  k_cpart2<<<nbk, 256, 0, stream>>>(src, dst, ew, bc_s, cbase_s, bc_d, cbase_d,
                                    recs_s, recs_d, E);
  k_finecomb<<<NB, 256, 0, stream>>>(recs_d, cbase_d, recs_s, cbase_s, esw, offs,
                                     ndst, nsrc, N);
  k_wsplit2<<<(D0 * D1 + D1 * D2 + 255) / 256, 256, 0, stream>>>(W1, wt1h, wt1l,
                                                                 W2, wt2h, wt2l);

  // layer 1: 256 -> 128 (MFMA)
  k_gemm_mfma<D0, D1, 2, 2><<<(N + 127) / 128, 256, 0, stream>>>(b_z, nsrc, wt1h, wt1l, h1, N);
  // layer-1 agg + layer-2 projection fused (writes h2 directly, no z1)
  k_agg128f<<<(N + 15) / 16, 256, 0, stream>>>(h1, offs, esw, ndst, b1, nsrc,
                                               wt2h, wt2l, h2, N);
  // layer-2 agg fused with layer-3 projection (64->1 matvec)
  k_agg64mv<<<(N + 15) / 16, 256, 0, stream>>>(h2, offs, esw, ndst, b2, W3, nsrc, h3, N);
  // final scalar aggregation
  k_aggfin<<<(N + 255) / 256, 256, 0, stream>>>(h3, offs, esw, ndst, b3, out, N);
}

// Round 13
// 314.812 us; speedup vs baseline: 1.3862x; 1.0613x over previous
//
#include <hip/hip_runtime.h>

// GCN decoder. Atomic-free CSR build (two-level counting sort) ->
// GEMM1(MFMA bf16-split) -> agg128 FUSED with GEMM2 (LDS mini-GEMM epilogue) ->
// agg64+matvec(W3) -> final scalar agg.
// Round 13: h2 stored fp16 (halves agg64mv's compulsory L2-fill traffic,
// 176->88MB); EBLK back to 4096 (cpart2 line efficiency). agg128f is pinned
// at the ~3.6TB/s random-512B-fill fabric ceiling (r10 vs r12 A/B evidence).

#include <hip/hip_fp16.h>

constexpr int D0 = 256, D1 = 128, D2 = 64;
constexpr int NB = 1024;   // coarse bins
constexpr int BSH = 7;     // bin = key >> 7 (128 nodes per bin)
constexpr int EBLK = 4096; // edges per block in hist/partition kernels

typedef __attribute__((ext_vector_type(2))) float f32x2;
typedef __attribute__((ext_vector_type(4))) float f32x4;
typedef __attribute__((ext_vector_type(8))) short short8;
typedef _Float16 h16x4 __attribute__((ext_vector_type(4)));

__device__ inline unsigned short f2bf(float f) {
  unsigned u = __builtin_bit_cast(unsigned, f);
  u += 0x7fffu + ((u >> 16) & 1u);
  return (unsigned short)(u >> 16);
}
__device__ inline float bf2f(unsigned short h) {
  unsigned u = ((unsigned)h) << 16;
  return __builtin_bit_cast(float, u);
}
__device__ inline int rdlane_i(int v, int l) { return __builtin_amdgcn_readlane(v, l); }

// ---------------- merged coarse histograms: src and dst in one edge pass ----------------
__global__ void k_chist2(const int* __restrict__ src, const int* __restrict__ dst,
                         int* __restrict__ bc_s, int* __restrict__ bc_d, int E) {
  __shared__ int hs[NB], hd[NB];
  for (int i = threadIdx.x; i < NB; i += 256) { hs[i] = 0; hd[i] = 0; }
  __syncthreads();
  int e0 = blockIdx.x * EBLK, e1 = min(e0 + EBLK, E);
  for (int i = e0 + threadIdx.x; i < e1; i += 256) {
    atomicAdd(&hs[src[i] >> BSH], 1);
    atomicAdd(&hd[dst[i] >> BSH], 1);
  }
  __syncthreads();
  for (int i = threadIdx.x; i < NB; i += 256) {
    bc_s[blockIdx.x * NB + i] = hs[i];
    bc_d[blockIdx.x * NB + i] = hd[i];
  }
}

// ---------------- coalesced column scan: block = 16 consecutive bins ----------------
__global__ void k_binscan(int* __restrict__ bc_s, int* __restrict__ bt_s,
                          int* __restrict__ bc_d, int* __restrict__ bt_d, int nbk) {
  __shared__ int part[16][17];
  int* bc = blockIdx.y ? bc_d : bc_s;
  int* bt = blockIdx.y ? bt_d : bt_s;
  const int j = threadIdx.x & 15;
  const int c = threadIdx.x >> 4;
  const int bin = blockIdx.x * 16 + j;
  const int chunk = (nbk + 15) / 16;
  const int r0 = c * chunk, r1 = min(r0 + chunk, nbk);
  int s = 0;
  for (int b = r0; b < r1; ++b) s += bc[b * NB + bin];
  part[c][j] = s;
  __syncthreads();
  int pre = 0;
  for (int q = 0; q < c; ++q) pre += part[q][j];
  int run = pre;
  for (int b = r0; b < r1; ++b) {
    int v = bc[b * NB + bin];
    bc[b * NB + bin] = run;
    run += v;
  }
  if (c == 15) bt[bin] = run;
}

// ---------------- scan of 1024 bin totals (block 0: src, block 1: dst) ----------------
__global__ void k_btscan(const int* __restrict__ bt_s, int* __restrict__ cbase_s,
                         const int* __restrict__ bt_d, int* __restrict__ cbase_d,
                         int* __restrict__ offs_end, int E) {
  __shared__ int wsum[16];
  const int* bt = blockIdx.x ? bt_d : bt_s;
  int* cbase = blockIdx.x ? cbase_d : cbase_s;
  int tid = threadIdx.x, lane = tid & 63, wid = tid >> 6;
  int v = bt[tid];
  int x = v;
#pragma unroll
  for (int d = 1; d < 64; d <<= 1) { int t = __shfl_up(x, d); if (lane >= d) x += t; }
  if (lane == 63) wsum[wid] = x;
  __syncthreads();
  if (wid == 0 && lane < 16) {
    int s = wsum[lane];
#pragma unroll
    for (int d = 1; d < 16; d <<= 1) { int t = __shfl_up(s, d, 16); if (lane >= d) s += t; }
    wsum[lane] = s;
  }
  __syncthreads();
  int excl = x - v + (wid ? wsum[wid - 1] : 0);
  cbase[tid] = excl;
  if (tid == NB - 1) cbase[NB] = E;
  if (blockIdx.x == 1 && tid == 0) *offs_end = E;
}

// ---------------- merged coarse partition: one edge pass, both sides ----------------
__global__ void k_cpart2(const int* __restrict__ src, const int* __restrict__ dst,
                         const float* __restrict__ ew,
                         const int* __restrict__ bc_s, const int* __restrict__ cbase_s,
                         const int* __restrict__ bc_d, const int* __restrict__ cbase_d,
                         int* __restrict__ recs_s, int2* __restrict__ recs_d, int E) {
  __shared__ int cs[NB], cd[NB];
  for (int i = threadIdx.x; i < NB; i += 256) {
    cs[i] = cbase_s[i] + bc_s[blockIdx.x * NB + i];
    cd[i] = cbase_d[i] + bc_d[blockIdx.x * NB + i];
  }
  __syncthreads();
  int e0 = blockIdx.x * EBLK, e1 = min(e0 + EBLK, E);
  for (int i = e0 + threadIdx.x; i < e1; i += 256) {
    int s = src[i], d = dst[i];
    int ps = atomicAdd(&cs[s >> BSH], 1);
    recs_s[ps] = s;
    int pd = atomicAdd(&cd[d >> BSH], 1);
    recs_d[pd] = int2{s | ((d & 127) << 17), __builtin_bit_cast(int, ew[i])};
  }
}

// ---------------- merged fine pass: dst CSR (offs, nd, esw) + src hist (ns) ----------------
__global__ void k_finecomb(const int2* __restrict__ recs_d, const int* __restrict__ cbase_d,
                           const int* __restrict__ recs_s, const int* __restrict__ cbase_s,
                           int2* __restrict__ esw, int* __restrict__ offs,
                           float* __restrict__ nd, float* __restrict__ ns, int N) {
  __shared__ int h[128], cur[128];
  __shared__ int w0tot;
  int bin = blockIdx.x;
  int r0 = cbase_d[bin], r1 = cbase_d[bin + 1];
  int t = threadIdx.x;
  if (t < 128) h[t] = 0;
  __syncthreads();
  for (int i = r0 + t; i < r1; i += 256) atomicAdd(&h[recs_d[i].x >> 17], 1);
  __syncthreads();
  int v = 0, x = 0;
  if (t < 128) {
    v = h[t];
    x = v;
#pragma unroll
    for (int d = 1; d < 64; d <<= 1) { int tt = __shfl_up(x, d); if ((t & 63) >= d) x += tt; }
    if (t == 63) w0tot = x;
  }
  __syncthreads();
  if (t < 128) {
    int excl = x - v + (t >= 64 ? w0tot : 0);
    int node = bin * 128 + t;
    if (node < N) {
      offs[node] = r0 + excl;
      int d = v < 1 ? 1 : v;
      nd[node] = (float)(1.0 / sqrt((double)d));
    }
    cur[t] = r0 + excl;
  }
  __syncthreads();
  for (int i = r0 + t; i < r1; i += 256) {
    int2 rc = recs_d[i];
    int p = atomicAdd(&cur[rc.x >> 17], 1);
    esw[p] = int2{rc.x & 0x1ffff, rc.y};
  }
  // ---- src side: out-degree histogram -> ns ----
  __syncthreads();
  if (t < 128) h[t] = 0;
  __syncthreads();
  int s0 = cbase_s[bin], s1 = cbase_s[bin + 1];
  for (int i = s0 + t; i < s1; i += 256) atomicAdd(&h[recs_s[i] & 127], 1);
  __syncthreads();
  if (t < 128) {
    int node = bin * 128 + t;
    if (node < N) {
      int d = h[t] < 1 ? 1 : h[t];
      ns[node] = (float)(1.0 / sqrt((double)d));
    }
  }
}

// ---------------- merged W split: W1 and W2 -> transposed bf16 hi/lo planes ----------------
__global__ void k_wsplit2(const float* __restrict__ W1, short* __restrict__ w1h,
                          short* __restrict__ w1l, const float* __restrict__ W2,
                          short* __restrict__ w2h, short* __restrict__ w2l) {
  int t = blockIdx.x * blockDim.x + threadIdx.x;
  if (t < D0 * D1) {
    int k = t / D1, n = t % D1;
    float f = W1[t];
    unsigned short h = f2bf(f);
    w1h[(size_t)n * D0 + k] = (short)h;
    w1l[(size_t)n * D0 + k] = (short)f2bf(f - bf2f(h));
  } else if (t < D0 * D1 + D1 * D2) {
    int i = t - D0 * D1;
    int k = i / D2, n = i % D2;
    float f = W2[i];
    unsigned short h = f2bf(f);
    w2h[(size_t)n * D1 + k] = (short)h;
    w2l[(size_t)n * D1 + k] = (short)f2bf(f - bf2f(h));
  }
}

// ---------------- MFMA GEMM (layer 1): C[M,N] = (A * ns[:,None]) @ W ----------------
template <int K, int N, int WR, int WC>
__launch_bounds__(256, 2)
__global__ void k_gemm_mfma(const float* __restrict__ A, const float* __restrict__ ns,
                            const short* __restrict__ Wth, const short* __restrict__ Wtl,
                            float* __restrict__ C, int M) {
  constexpr int MR = 128 / WR / 16;
  constexpr int NC = N / WC / 16;
  __shared__ short8 Ah[4 * 128], Al[4 * 128];
  __shared__ short8 Bh[4 * N], Bl[4 * N];
  const int t = threadIdx.x;
  const int block_row = blockIdx.x * 128;
  const int lane = t & 63, wid = t >> 6;
  const int wr = wid / WC, wc = wid % WC;
  const int rowbase = wr * (128 / WR), colbase = wc * (N / WC);
  const int c = lane >> 4, lr = lane & 15;
  f32x4 acc[MR][NC] = {};
  const int r = t & 127;
  const int grow = block_row + r;
  float nsv = 0.f;
  if (t < 128 && grow < M) nsv = ns[grow];

  for (int k0 = 0; k0 < K; k0 += 32) {
    if (t < 128) {
      f32x4 v[8];
      if (grow < M) {
        const f32x4* ap = (const f32x4*)(A + (size_t)grow * K + k0);
#pragma unroll
        for (int i = 0; i < 8; ++i) v[i] = ap[i] * nsv;
      } else {
#pragma unroll
        for (int i = 0; i < 8; ++i) v[i] = f32x4{0.f, 0.f, 0.f, 0.f};
      }
#pragma unroll
      for (int cc = 0; cc < 4; ++cc) {
        short8 hi, lo;
#pragma unroll
        for (int i = 0; i < 8; ++i) {
          float f = v[cc * 2 + (i >> 2)][i & 3];
          unsigned short h = f2bf(f);
          hi[i] = (short)h;
          lo[i] = (short)f2bf(f - bf2f(h));
        }
        Ah[cc * 128 + r] = hi;
        Al[cc * 128 + r] = lo;
      }
    } else {
      const int tt = t - 128;
#pragma unroll
      for (int id = tt; id < N * 4; id += 128) {
        int col = id & (N - 1);
        int cb = id / N;
        Bh[cb * N + col] = *(const short8*)(Wth + (size_t)col * K + k0 + cb * 8);
        Bl[cb * N + col] = *(const short8*)(Wtl + (size_t)col * K + k0 + cb * 8);
      }
    }
    __syncthreads();
    short8 ah[MR], al[MR], bh[NC], bl[NC];
#pragma unroll
    for (int m = 0; m < MR; ++m) {
      int row = rowbase + m * 16 + lr;
      ah[m] = Ah[c * 128 + row];
      al[m] = Al[c * 128 + row];
    }
#pragma unroll
    for (int n = 0; n < NC; ++n) {
      int col = colbase + n * 16 + lr;
      bh[n] = Bh[c * N + col];
      bl[n] = Bl[c * N + col];
    }
#pragma unroll
    for (int m = 0; m < MR; ++m)
#pragma unroll
      for (int n = 0; n < NC; ++n) {
        acc[m][n] = __builtin_amdgcn_mfma_f32_16x16x32_bf16(ah[m], bh[n], acc[m][n], 0, 0, 0);
        acc[m][n] = __builtin_amdgcn_mfma_f32_16x16x32_bf16(ah[m], bl[n], acc[m][n], 0, 0, 0);
        acc[m][n] = __builtin_amdgcn_mfma_f32_16x16x32_bf16(al[m], bh[n], acc[m][n], 0, 0, 0);
      }
    __syncthreads();
  }
#pragma unroll
  for (int m = 0; m < MR; ++m) {
#pragma unroll
    for (int j = 0; j < 4; ++j) {
      int row = block_row + rowbase + m * 16 + (lane >> 4) * 4 + j;
      if (row < M) {
#pragma unroll
        for (int n = 0; n < NC; ++n)
          C[(size_t)row * N + colbase + n * 16 + lr] = acc[m][n][j];
      }
    }
  }
}

// ---------------- FUSED agg128 + GEMM2: LDS-staged edge meta, 2 edges/wave-load ----------------
// Half-wave per edge: p=lane&31 covers features 4p..4p+3 (f32x4); halves combined
// via shfl_xor(32). h2 written as fp16 (halves layer-2 gather traffic).
__launch_bounds__(256, 4)
__global__ void k_agg128f(const float* __restrict__ h, const int* __restrict__ offs,
                          const int2* __restrict__ esw, const float* __restrict__ nd,
                          const float* __restrict__ b1v, const float* __restrict__ ns,
                          const short* __restrict__ w2h, const short* __restrict__ w2l,
                          _Float16* __restrict__ h2, int M) {
  __shared__ unsigned Ah32[16 * 64], Al32[16 * 64];
  __shared__ int2 emeta[4][64];
  const int t = threadIdx.x, lane = t & 63, wid = t >> 6;
  const int base = blockIdx.x * 16;
  const int nb0 = base + wid * 4;
  const f32x4* hp4 = (const f32x4*)h;
  const int p = lane & 31;
  const int hi = lane >> 5;
  f32x4 bv = ((const f32x4*)b1v)[p];
  int ov = offs[min(nb0 + min(lane, 5), M)];
  int S0[4], S1[4];
#pragma unroll
  for (int q = 0; q < 4; ++q) { S0[q] = rdlane_i(ov, q); S1[q] = rdlane_i(ov, q + 1); }
  int2 ecur{0, 0};
  { int kk = S0[0] + lane; if (kk < S1[0]) ecur = esw[kk]; }
#pragma unroll
  for (int q = 0; q < 4; ++q) {
    const int row = wid * 4 + q;
    const int node = nb0 + q;
    int2 enxt{0, 0};
    if (q < 3) { int kk = S0[q + 1] + lane; if (kk < S1[q + 1]) enxt = esw[kk]; }
    unsigned hw0 = 0, hw1 = 0, lw0 = 0, lw1 = 0;
    if (node < M) {
      const int s0 = S0[q], s1 = S1[q];
      f32x4 acc = {};
      int2 e = ecur;
      for (int bb = s0; bb < s1; bb += 64) {
        if (bb != s0) { int kk = bb + lane; e = (kk < s1) ? esw[kk] : int2{0, 0}; }
        emeta[wid][lane] = e;  // per-wave buffer; in-order LDS pipe, no barrier
        int cnt = min(64, s1 - bb);
        for (int jj = 0; jj < cnt; jj += 16) {
          int2 em[8];
          f32x4 v[8];
#pragma unroll
          for (int u = 0; u < 8; ++u) em[u] = emeta[wid][jj + 2 * u + hi];
#pragma unroll
          for (int u = 0; u < 8; ++u)
            v[u] = hp4[(size_t)(unsigned)em[u].x * 32 + p];
          __builtin_amdgcn_sched_barrier(0);  // keep all 8 x 1KB gathers in flight
#pragma unroll
          for (int u = 0; u < 8; ++u) {
            float wu = __builtin_bit_cast(float, em[u].y);
            acc[0] += v[u][0] * wu;
            acc[1] += v[u][1] * wu;
            acc[2] += v[u][2] * wu;
            acc[3] += v[u][3] * wu;
          }
        }
      }
      f32x4 o;
#pragma unroll
      for (int i = 0; i < 4; ++i) o[i] = acc[i] + __shfl_xor(acc[i], 32);
      float ndv = nd[node], nsv = ns[node];
      float z[4];
#pragma unroll
      for (int i = 0; i < 4; ++i) z[i] = fmaxf(o[i] * ndv + bv[i], 0.f) * nsv;
      unsigned short h0 = f2bf(z[0]), h1b = f2bf(z[1]), h2b = f2bf(z[2]), h3b = f2bf(z[3]);
      hw0 = (unsigned)h0 | ((unsigned)h1b << 16);
      hw1 = (unsigned)h2b | ((unsigned)h3b << 16);
      lw0 = (unsigned)f2bf(z[0] - bf2f(h0)) | ((unsigned)f2bf(z[1] - bf2f(h1b)) << 16);
      lw1 = (unsigned)f2bf(z[2] - bf2f(h2b)) | ((unsigned)f2bf(z[3] - bf2f(h3b)) << 16);
    }
    if (lane < 32) {
      int widx = (2 * p) ^ ((row & 7) << 2);  // XOR swizzle, preserves word pairing
      *(uint2*)&Ah32[row * 64 + widx] = uint2{hw0, hw1};
      *(uint2*)&Al32[row * 64 + widx] = uint2{lw0, lw1};
    }
    ecur = enxt;
  }
  __syncthreads();
  // B-frags for this wave's 16-col tile of W2 ([64][128] bf16 planes)
  const int colB = wid * 16 + (lane & 15);
  const int koff = (lane >> 4) * 8;
  short8 bh[4], bl[4];
#pragma unroll
  for (int ks = 0; ks < 4; ++ks) {
    bh[ks] = *(const short8*)(w2h + (size_t)colB * 128 + ks * 32 + koff);
    bl[ks] = *(const short8*)(w2l + (size_t)colB * 128 + ks * 32 + koff);
  }
  const int arow = lane & 15, ac = lane >> 4;
  f32x4 acc = {};
#pragma unroll
  for (int ks = 0; ks < 4; ++ks) {
    int bidx = arow * 64 + ((ks * 16 + ac * 4) ^ ((arow & 7) << 2));
    short8 ah = *(const short8*)(Ah32 + bidx);
    short8 al = *(const short8*)(Al32 + bidx);
    acc = __builtin_amdgcn_mfma_f32_16x16x32_bf16(ah, bh[ks], acc, 0, 0, 0);
    acc = __builtin_amdgcn_mfma_f32_16x16x32_bf16(ah, bl[ks], acc, 0, 0, 0);
    acc = __builtin_amdgcn_mfma_f32_16x16x32_bf16(al, bh[ks], acc, 0, 0, 0);
  }
  const int crow = (lane >> 4) * 4;
  const int col = wid * 16 + (lane & 15);
#pragma unroll
  for (int j = 0; j < 4; ++j) {
    int node = base + crow + j;
    if (node < M) h2[(size_t)node * 64 + col] = (_Float16)acc[j];
  }
}

// ---------------- agg64+matvec: fp16 h2 gather, 4 edges/wave-load ----------------
// Quarter-wave per edge: p=lane&15 covers feats 4p..4p+3 as 4 halves (8B load).
__global__ void k_agg64mv(const _Float16* __restrict__ h2, const int* __restrict__ offs,
                          const int2* __restrict__ esw, const float* __restrict__ nd,
                          const float* __restrict__ b2, const float* __restrict__ W3,
                          const float* __restrict__ ns, float* __restrict__ h3, int M) {
  __shared__ int2 emeta[4][64];
  const int lane = threadIdx.x & 63, wid = threadIdx.x >> 6;
  const int wave = blockIdx.x * (blockDim.x >> 6) + wid;
  const int nb0 = wave * 4;
  if (nb0 >= M) return;
  const uint2* hp = (const uint2*)h2;  // 8B = 4 fp16
  const int p = lane & 15;
  const int q4 = lane >> 4;
  f32x4 bv = ((const f32x4*)b2)[p];
  f32x4 w3v = ((const f32x4*)W3)[p];
  int ov = offs[min(nb0 + min(lane, 5), M)];
  int S0[4], S1[4];
#pragma unroll
  for (int q = 0; q < 4; ++q) { S0[q] = rdlane_i(ov, q); S1[q] = rdlane_i(ov, q + 1); }
  int2 ecur{0, 0};
  { int kk = S0[0] + lane; if (kk < S1[0]) ecur = esw[kk]; }
#pragma unroll
  for (int q = 0; q < 4; ++q) {
    const int node = nb0 + q;
    int2 enxt{0, 0};
    if (q < 3) { int kk = S0[q + 1] + lane; if (kk < S1[q + 1]) enxt = esw[kk]; }
    if (node < M) {
      const int s0 = S0[q], s1 = S1[q];
      f32x4 acc = {};
      int2 e = ecur;
      for (int bb = s0; bb < s1; bb += 64) {
        if (bb != s0) { int kk = bb + lane; e = (kk < s1) ? esw[kk] : int2{0, 0}; }
        emeta[wid][lane] = e;
        int cnt = min(64, s1 - bb);
        for (int jj = 0; jj < cnt; jj += 32) {
          int2 em[8];
          uint2 v[8];
#pragma unroll
          for (int u = 0; u < 8; ++u) em[u] = emeta[wid][jj + 4 * u + q4];
#pragma unroll
          for (int u = 0; u < 8; ++u)
            v[u] = hp[(size_t)(unsigned)em[u].x * 16 + p];
          __builtin_amdgcn_sched_barrier(0);
#pragma unroll
          for (int u = 0; u < 8; ++u) {
            float wu = __builtin_bit_cast(float, em[u].y);
            h16x4 hv = __builtin_bit_cast(h16x4, v[u]);
            acc[0] += (float)hv[0] * wu;
            acc[1] += (float)hv[1] * wu;
            acc[2] += (float)hv[2] * wu;
            acc[3] += (float)hv[3] * wu;
          }
        }
      }
#pragma unroll
      for (int i = 0; i < 4; ++i) {
        acc[i] += __shfl_xor(acc[i], 16);
        acc[i] += __shfl_xor(acc[i], 32);
      }
      float ndv = nd[node];
      float dp = 0.f;
#pragma unroll
      for (int i = 0; i < 4; ++i) dp += fmaxf(acc[i] * ndv + bv[i], 0.f) * w3v[i];
#pragma unroll
      for (int d = 8; d; d >>= 1) dp += __shfl_xor(dp, d);
      if (lane == 0) h3[node] = dp * ns[node];
    }
    ecur = enxt;
  }
}

// ---------------- final scalar aggregation: 16-deep batched gathers ----------------
__launch_bounds__(256)
__global__ void k_aggfin(const float* __restrict__ h3, const int* __restrict__ offs,
                         const int2* __restrict__ esw, const float* __restrict__ nd,
                         const float* __restrict__ b3, float* __restrict__ out, int M) {
  int i = blockIdx.x * blockDim.x + threadIdx.x;
  if (i >= M) return;
  int s0 = offs[i], s1 = offs[i + 1];
  float acc = 0.f;
  for (int k0 = s0; k0 < s1; k0 += 16) {
    int nn = min(16, s1 - k0);
    int2 e[16];
    float hv[16];
#pragma unroll
    for (int u = 0; u < 16; ++u) e[u] = esw[k0 + min(u, nn - 1)];
#pragma unroll
    for (int u = 0; u < 16; ++u) hv[u] = h3[e[u].x];
    __builtin_amdgcn_sched_barrier(0);
#pragma unroll
    for (int u = 0; u < 16; ++u)
      if (u < nn) acc += hv[u] * __builtin_bit_cast(float, e[u].y);
  }
  out[i] = acc * nd[i] + b3[0];
}

extern "C" void kernel_launch(void* const* d_in, const int* in_sizes, int n_in,
                              void* d_out, int out_size, void* d_ws, size_t ws_size,
                              hipStream_t stream) {
  const float* b_z = (const float*)d_in[0];
  const int*   src = (const int*)d_in[1];
  const int*   dst = (const int*)d_in[2];
  const float* ew  = (const float*)d_in[3];
  const float* W1  = (const float*)d_in[5];
  const float* b1  = (const float*)d_in[6];
  const float* W2  = (const float*)d_in[7];
  const float* b2  = (const float*)d_in[8];
  const float* W3  = (const float*)d_in[9];
  const float* b3  = (const float*)d_in[10];
  const int N = in_sizes[0] / D0;
  const int E = in_sizes[1];
  float* out = (float*)d_out;

  char* ws = (char*)d_ws;
  size_t off_b = 0;
  auto alloc = [&](size_t bytes) -> void* {
    void* p = ws + off_b;
    off_b += (bytes + 255) & ~(size_t)255;
    return p;
  };
  const int nbk = (E + EBLK - 1) / EBLK;
  int*   bc_s    = (int*)alloc((size_t)nbk * NB * 4);
  int*   bc_d    = (int*)alloc((size_t)nbk * NB * 4);
  int*   bt_s    = (int*)alloc((size_t)NB * 4);
  int*   bt_d    = (int*)alloc((size_t)NB * 4);
  int*   cbase_s = (int*)alloc((size_t)(NB + 1) * 4);
  int*   cbase_d = (int*)alloc((size_t)(NB + 1) * 4);
  int*   offs    = (int*)alloc((size_t)(N + 1) * 4);
  int2*  esw     = (int2*)alloc((size_t)E * 8);
  float* nsrc    = (float*)alloc((size_t)N * 4);
  float* ndst    = (float*)alloc((size_t)N * 4);
  float* h1      = (float*)alloc((size_t)N * D1 * 4);   // 51.2 MB
  _Float16* h2   = (_Float16*)alloc((size_t)N * D2 * 2); // 12.8 MB (fp16)
  float* h3      = (float*)alloc((size_t)N * 4);
  short* wt1h    = (short*)alloc((size_t)D0 * D1 * 2);
  short* wt1l    = (short*)alloc((size_t)D0 * D1 * 2);
  short* wt2h    = (short*)alloc((size_t)D1 * D2 * 2);
  short* wt2l    = (short*)alloc((size_t)D1 * D2 * 2);
  // partition records alias h1 (both dead before GEMM1 writes h1)
  int2*  recs_d = (int2*)h1;                              // E*8 = 12.8 MB
  int*   recs_s = (int*)((char*)h1 + ((size_t)16 << 20)); // E*4 = 6.4 MB @ +16MB

  // --- CSR build (atomic-free, fully parallel) ---
  k_chist2<<<nbk, 256, 0, stream>>>(src, dst, bc_s, bc_d, E);
  k_binscan<<<dim3(NB / 16, 2), 256, 0, stream>>>(bc_s, bt_s, bc_d, bt_d, nbk);
  k_btscan<<<2, 1024, 0, stream>>>(bt_s, cbase_s, bt_d, cbase_d, &offs[N], E);
  k_cpart2<<<nbk, 256, 0, stream>>>(src, dst, ew, bc_s, cbase_s, bc_d, cbase_d,
                                    recs_s, recs_d, E);
  k_finecomb<<<NB, 256, 0, stream>>>(recs_d, cbase_d, recs_s, cbase_s, esw, offs,
                                     ndst, nsrc, N);
  k_wsplit2<<<(D0 * D1 + D1 * D2 + 255) / 256, 256, 0, stream>>>(W1, wt1h, wt1l,
                                                                 W2, wt2h, wt2l);

  // layer 1: 256 -> 128 (MFMA)
  k_gemm_mfma<D0, D1, 2, 2><<<(N + 127) / 128, 256, 0, stream>>>(b_z, nsrc, wt1h, wt1l, h1, N);
  // layer-1 agg + layer-2 projection fused (writes fp16 h2 directly, no z1)
  k_agg128f<<<(N + 15) / 16, 256, 0, stream>>>(h1, offs, esw, ndst, b1, nsrc,
                                               wt2h, wt2l, h2, N);
  // layer-2 agg fused with layer-3 projection (64->1 matvec), fp16 gathers
  k_agg64mv<<<(N + 15) / 16, 256, 0, stream>>>(h2, offs, esw, ndst, b2, W3, nsrc, h3, N);
  // final scalar aggregation
  k_aggfin<<<(N + 255) / 256, 256, 0, stream>>>(h3, offs, esw, ndst, b3, out, N);
}

// Round 14
// 273.328 us; speedup vs baseline: 1.5966x; 1.1518x over previous
//
#include <hip/hip_runtime.h>
#include <hip/hip_fp16.h>

// GCN decoder. Atomic-free CSR build (two-level counting sort) ->
// GEMM1(MFMA bf16-split, fp16 out) -> agg128(fp16 gather) FUSED with GEMM2
// (LDS mini-GEMM epilogue, fp16 out) -> agg64+matvec(W3) -> final scalar agg.
// Round 14: h1 stored fp16 -> halves agg128f's compulsory per-XCD L2-fill
// (381MB -> ~200MB). r10-vs-r12 A/B showed agg128f is fill-byte-bound.

constexpr int D0 = 256, D1 = 128, D2 = 64;
constexpr int NB = 1024;   // coarse bins
constexpr int BSH = 7;     // bin = key >> 7 (128 nodes per bin)
constexpr int EBLK = 4096; // edges per block in hist/partition kernels

typedef __attribute__((ext_vector_type(2))) float f32x2;
typedef __attribute__((ext_vector_type(4))) float f32x4;
typedef __attribute__((ext_vector_type(8))) short short8;
typedef _Float16 h16x4 __attribute__((ext_vector_type(4)));

__device__ inline unsigned short f2bf(float f) {
  unsigned u = __builtin_bit_cast(unsigned, f);
  u += 0x7fffu + ((u >> 16) & 1u);
  return (unsigned short)(u >> 16);
}
__device__ inline float bf2f(unsigned short h) {
  unsigned u = ((unsigned)h) << 16;
  return __builtin_bit_cast(float, u);
}
__device__ inline int rdlane_i(int v, int l) { return __builtin_amdgcn_readlane(v, l); }

// ---------------- merged coarse histograms: src and dst in one edge pass ----------------
__global__ void k_chist2(const int* __restrict__ src, const int* __restrict__ dst,
                         int* __restrict__ bc_s, int* __restrict__ bc_d, int E) {
  __shared__ int hs[NB], hd[NB];
  for (int i = threadIdx.x; i < NB; i += 256) { hs[i] = 0; hd[i] = 0; }
  __syncthreads();
  int e0 = blockIdx.x * EBLK, e1 = min(e0 + EBLK, E);
  for (int i = e0 + threadIdx.x; i < e1; i += 256) {
    atomicAdd(&hs[src[i] >> BSH], 1);
    atomicAdd(&hd[dst[i] >> BSH], 1);
  }
  __syncthreads();
  for (int i = threadIdx.x; i < NB; i += 256) {
    bc_s[blockIdx.x * NB + i] = hs[i];
    bc_d[blockIdx.x * NB + i] = hd[i];
  }
}

// ---------------- coalesced column scan: block = 16 consecutive bins ----------------
__global__ void k_binscan(int* __restrict__ bc_s, int* __restrict__ bt_s,
                          int* __restrict__ bc_d, int* __restrict__ bt_d, int nbk) {
  __shared__ int part[16][17];
  int* bc = blockIdx.y ? bc_d : bc_s;
  int* bt = blockIdx.y ? bt_d : bt_s;
  const int j = threadIdx.x & 15;
  const int c = threadIdx.x >> 4;
  const int bin = blockIdx.x * 16 + j;
  const int chunk = (nbk + 15) / 16;
  const int r0 = c * chunk, r1 = min(r0 + chunk, nbk);
  int s = 0;
  for (int b = r0; b < r1; ++b) s += bc[b * NB + bin];
  part[c][j] = s;
  __syncthreads();
  int pre = 0;
  for (int q = 0; q < c; ++q) pre += part[q][j];
  int run = pre;
  for (int b = r0; b < r1; ++b) {
    int v = bc[b * NB + bin];
    bc[b * NB + bin] = run;
    run += v;
  }
  if (c == 15) bt[bin] = run;
}

// ---------------- scan of 1024 bin totals (block 0: src, block 1: dst) ----------------
__global__ void k_btscan(const int* __restrict__ bt_s, int* __restrict__ cbase_s,
                         const int* __restrict__ bt_d, int* __restrict__ cbase_d,
                         int* __restrict__ offs_end, int E) {
  __shared__ int wsum[16];
  const int* bt = blockIdx.x ? bt_d : bt_s;
  int* cbase = blockIdx.x ? cbase_d : cbase_s;
  int tid = threadIdx.x, lane = tid & 63, wid = tid >> 6;
  int v = bt[tid];
  int x = v;
#pragma unroll
  for (int d = 1; d < 64; d <<= 1) { int t = __shfl_up(x, d); if (lane >= d) x += t; }
  if (lane == 63) wsum[wid] = x;
  __syncthreads();
  if (wid == 0 && lane < 16) {
    int s = wsum[lane];
#pragma unroll
    for (int d = 1; d < 16; d <<= 1) { int t = __shfl_up(s, d, 16); if (lane >= d) s += t; }
    wsum[lane] = s;
  }
  __syncthreads();
  int excl = x - v + (wid ? wsum[wid - 1] : 0);
  cbase[tid] = excl;
  if (tid == NB - 1) cbase[NB] = E;
  if (blockIdx.x == 1 && tid == 0) *offs_end = E;
}

// ---------------- merged coarse partition: one edge pass, both sides ----------------
__global__ void k_cpart2(const int* __restrict__ src, const int* __restrict__ dst,
                         const float* __restrict__ ew,
                         const int* __restrict__ bc_s, const int* __restrict__ cbase_s,
                         const int* __restrict__ bc_d, const int* __restrict__ cbase_d,
                         int* __restrict__ recs_s, int2* __restrict__ recs_d, int E) {
  __shared__ int cs[NB], cd[NB];
  for (int i = threadIdx.x; i < NB; i += 256) {
    cs[i] = cbase_s[i] + bc_s[blockIdx.x * NB + i];
    cd[i] = cbase_d[i] + bc_d[blockIdx.x * NB + i];
  }
  __syncthreads();
  int e0 = blockIdx.x * EBLK, e1 = min(e0 + EBLK, E);
  for (int i = e0 + threadIdx.x; i < e1; i += 256) {
    int s = src[i], d = dst[i];
    int ps = atomicAdd(&cs[s >> BSH], 1);
    recs_s[ps] = s;
    int pd = atomicAdd(&cd[d >> BSH], 1);
    recs_d[pd] = int2{s | ((d & 127) << 17), __builtin_bit_cast(int, ew[i])};
  }
}

// ---------------- merged fine pass: dst CSR (offs, nd, esw) + src hist (ns) ----------------
__global__ void k_finecomb(const int2* __restrict__ recs_d, const int* __restrict__ cbase_d,
                           const int* __restrict__ recs_s, const int* __restrict__ cbase_s,
                           int2* __restrict__ esw, int* __restrict__ offs,
                           float* __restrict__ nd, float* __restrict__ ns, int N) {
  __shared__ int h[128], cur[128];
  __shared__ int w0tot;
  int bin = blockIdx.x;
  int r0 = cbase_d[bin], r1 = cbase_d[bin + 1];
  int t = threadIdx.x;
  if (t < 128) h[t] = 0;
  __syncthreads();
  for (int i = r0 + t; i < r1; i += 256) atomicAdd(&h[recs_d[i].x >> 17], 1);
  __syncthreads();
  int v = 0, x = 0;
  if (t < 128) {
    v = h[t];
    x = v;
#pragma unroll
    for (int d = 1; d < 64; d <<= 1) { int tt = __shfl_up(x, d); if ((t & 63) >= d) x += tt; }
    if (t == 63) w0tot = x;
  }
  __syncthreads();
  if (t < 128) {
    int excl = x - v + (t >= 64 ? w0tot : 0);
    int node = bin * 128 + t;
    if (node < N) {
      offs[node] = r0 + excl;
      int d = v < 1 ? 1 : v;
      nd[node] = (float)(1.0 / sqrt((double)d));
    }
    cur[t] = r0 + excl;
  }
  __syncthreads();
  for (int i = r0 + t; i < r1; i += 256) {
    int2 rc = recs_d[i];
    int p = atomicAdd(&cur[rc.x >> 17], 1);
    esw[p] = int2{rc.x & 0x1ffff, rc.y};
  }
  // ---- src side: out-degree histogram -> ns ----
  __syncthreads();
  if (t < 128) h[t] = 0;
  __syncthreads();
  int s0 = cbase_s[bin], s1 = cbase_s[bin + 1];
  for (int i = s0 + t; i < s1; i += 256) atomicAdd(&h[recs_s[i] & 127], 1);
  __syncthreads();
  if (t < 128) {
    int node = bin * 128 + t;
    if (node < N) {
      int d = h[t] < 1 ? 1 : h[t];
      ns[node] = (float)(1.0 / sqrt((double)d));
    }
  }
}

// ---------------- merged W split: W1 and W2 -> transposed bf16 hi/lo planes ----------------
__global__ void k_wsplit2(const float* __restrict__ W1, short* __restrict__ w1h,
                          short* __restrict__ w1l, const float* __restrict__ W2,
                          short* __restrict__ w2h, short* __restrict__ w2l) {
  int t = blockIdx.x * blockDim.x + threadIdx.x;
  if (t < D0 * D1) {
    int k = t / D1, n = t % D1;
    float f = W1[t];
    unsigned short h = f2bf(f);
    w1h[(size_t)n * D0 + k] = (short)h;
    w1l[(size_t)n * D0 + k] = (short)f2bf(f - bf2f(h));
  } else if (t < D0 * D1 + D1 * D2) {
    int i = t - D0 * D1;
    int k = i / D2, n = i % D2;
    float f = W2[i];
    unsigned short h = f2bf(f);
    w2h[(size_t)n * D1 + k] = (short)h;
    w2l[(size_t)n * D1 + k] = (short)f2bf(f - bf2f(h));
  }
}

// ---------------- MFMA GEMM (layer 1): h1[M,N] = fp16((A * ns[:,None]) @ W) ----------------
template <int K, int N, int WR, int WC>
__launch_bounds__(256, 2)
__global__ void k_gemm_mfma(const float* __restrict__ A, const float* __restrict__ ns,
                            const short* __restrict__ Wth, const short* __restrict__ Wtl,
                            _Float16* __restrict__ C, int M) {
  constexpr int MR = 128 / WR / 16;
  constexpr int NC = N / WC / 16;
  __shared__ short8 Ah[4 * 128], Al[4 * 128];
  __shared__ short8 Bh[4 * N], Bl[4 * N];
  const int t = threadIdx.x;
  const int block_row = blockIdx.x * 128;
  const int lane = t & 63, wid = t >> 6;
  const int wr = wid / WC, wc = wid % WC;
  const int rowbase = wr * (128 / WR), colbase = wc * (N / WC);
  const int c = lane >> 4, lr = lane & 15;
  f32x4 acc[MR][NC] = {};
  const int r = t & 127;
  const int grow = block_row + r;
  float nsv = 0.f;
  if (t < 128 && grow < M) nsv = ns[grow];

  for (int k0 = 0; k0 < K; k0 += 32) {
    if (t < 128) {
      f32x4 v[8];
      if (grow < M) {
        const f32x4* ap = (const f32x4*)(A + (size_t)grow * K + k0);
#pragma unroll
        for (int i = 0; i < 8; ++i) v[i] = ap[i] * nsv;
      } else {
#pragma unroll
        for (int i = 0; i < 8; ++i) v[i] = f32x4{0.f, 0.f, 0.f, 0.f};
      }
#pragma unroll
      for (int cc = 0; cc < 4; ++cc) {
        short8 hi, lo;
#pragma unroll
        for (int i = 0; i < 8; ++i) {
          float f = v[cc * 2 + (i >> 2)][i & 3];
          unsigned short h = f2bf(f);
          hi[i] = (short)h;
          lo[i] = (short)f2bf(f - bf2f(h));
        }
        Ah[cc * 128 + r] = hi;
        Al[cc * 128 + r] = lo;
      }
    } else {
      const int tt = t - 128;
#pragma unroll
      for (int id = tt; id < N * 4; id += 128) {
        int col = id & (N - 1);
        int cb = id / N;
        Bh[cb * N + col] = *(const short8*)(Wth + (size_t)col * K + k0 + cb * 8);
        Bl[cb * N + col] = *(const short8*)(Wtl + (size_t)col * K + k0 + cb * 8);
      }
    }
    __syncthreads();
    short8 ah[MR], al[MR], bh[NC], bl[NC];
#pragma unroll
    for (int m = 0; m < MR; ++m) {
      int row = rowbase + m * 16 + lr;
      ah[m] = Ah[c * 128 + row];
      al[m] = Al[c * 128 + row];
    }
#pragma unroll
    for (int n = 0; n < NC; ++n) {
      int col = colbase + n * 16 + lr;
      bh[n] = Bh[c * N + col];
      bl[n] = Bl[c * N + col];
    }
#pragma unroll
    for (int m = 0; m < MR; ++m)
#pragma unroll
      for (int n = 0; n < NC; ++n) {
        acc[m][n] = __builtin_amdgcn_mfma_f32_16x16x32_bf16(ah[m], bh[n], acc[m][n], 0, 0, 0);
        acc[m][n] = __builtin_amdgcn_mfma_f32_16x16x32_bf16(ah[m], bl[n], acc[m][n], 0, 0, 0);
        acc[m][n] = __builtin_amdgcn_mfma_f32_16x16x32_bf16(al[m], bh[n], acc[m][n], 0, 0, 0);
      }
    __syncthreads();
  }
#pragma unroll
  for (int m = 0; m < MR; ++m) {
#pragma unroll
    for (int j = 0; j < 4; ++j) {
      int row = block_row + rowbase + m * 16 + (lane >> 4) * 4 + j;
      if (row < M) {
#pragma unroll
        for (int n = 0; n < NC; ++n)
          C[(size_t)row * N + colbase + n * 16 + lr] = (_Float16)acc[m][n][j];
      }
    }
  }
}

// ---------------- FUSED agg128 + GEMM2: fp16 h1 gather (256B rows), 2 edges/wave-load ----------------
// Half-wave per edge: p=lane&31 covers feats 4p..4p+3 as 4 fp16 (8B load);
// halves combined via shfl_xor(32). h2 written fp16.
__launch_bounds__(256, 4)
__global__ void k_agg128f(const _Float16* __restrict__ h1, const int* __restrict__ offs,
                          const int2* __restrict__ esw, const float* __restrict__ nd,
                          const float* __restrict__ b1v, const float* __restrict__ ns,
                          const short* __restrict__ w2h, const short* __restrict__ w2l,
                          _Float16* __restrict__ h2, int M) {
  __shared__ unsigned Ah32[16 * 64], Al32[16 * 64];
  __shared__ int2 emeta[4][64];
  const int t = threadIdx.x, lane = t & 63, wid = t >> 6;
  const int base = blockIdx.x * 16;
  const int nb0 = base + wid * 4;
  const uint2* hp = (const uint2*)h1;  // 8B = 4 fp16; row = 32 uint2
  const int p = lane & 31;
  const int hi = lane >> 5;
  f32x4 bv = ((const f32x4*)b1v)[p];
  int ov = offs[min(nb0 + min(lane, 5), M)];
  int S0[4], S1[4];
#pragma unroll
  for (int q = 0; q < 4; ++q) { S0[q] = rdlane_i(ov, q); S1[q] = rdlane_i(ov, q + 1); }
  int2 ecur{0, 0};
  { int kk = S0[0] + lane; if (kk < S1[0]) ecur = esw[kk]; }
#pragma unroll
  for (int q = 0; q < 4; ++q) {
    const int row = wid * 4 + q;
    const int node = nb0 + q;
    int2 enxt{0, 0};
    if (q < 3) { int kk = S0[q + 1] + lane; if (kk < S1[q + 1]) enxt = esw[kk]; }
    unsigned hw0 = 0, hw1 = 0, lw0 = 0, lw1 = 0;
    if (node < M) {
      const int s0 = S0[q], s1 = S1[q];
      f32x4 acc = {};
      int2 e = ecur;
      for (int bb = s0; bb < s1; bb += 64) {
        if (bb != s0) { int kk = bb + lane; e = (kk < s1) ? esw[kk] : int2{0, 0}; }
        emeta[wid][lane] = e;  // per-wave buffer; in-order LDS pipe, no barrier
        int cnt = min(64, s1 - bb);
        for (int jj = 0; jj < cnt; jj += 16) {
          int2 em[8];
          uint2 v[8];
#pragma unroll
          for (int u = 0; u < 8; ++u) em[u] = emeta[wid][jj + 2 * u + hi];
#pragma unroll
          for (int u = 0; u < 8; ++u)
            v[u] = hp[(size_t)(unsigned)em[u].x * 32 + p];
          __builtin_amdgcn_sched_barrier(0);  // keep all 8 x 512B gathers in flight
#pragma unroll
          for (int u = 0; u < 8; ++u) {
            float wu = __builtin_bit_cast(float, em[u].y);
            h16x4 hv = __builtin_bit_cast(h16x4, v[u]);
            acc[0] += (float)hv[0] * wu;
            acc[1] += (float)hv[1] * wu;
            acc[2] += (float)hv[2] * wu;
            acc[3] += (float)hv[3] * wu;
          }
        }
      }
      f32x4 o;
#pragma unroll
      for (int i = 0; i < 4; ++i) o[i] = acc[i] + __shfl_xor(acc[i], 32);
      float ndv = nd[node], nsv = ns[node];
      float z[4];
#pragma unroll
      for (int i = 0; i < 4; ++i) z[i] = fmaxf(o[i] * ndv + bv[i], 0.f) * nsv;
      unsigned short h0 = f2bf(z[0]), h1b = f2bf(z[1]), h2b = f2bf(z[2]), h3b = f2bf(z[3]);
      hw0 = (unsigned)h0 | ((unsigned)h1b << 16);
      hw1 = (unsigned)h2b | ((unsigned)h3b << 16);
      lw0 = (unsigned)f2bf(z[0] - bf2f(h0)) | ((unsigned)f2bf(z[1] - bf2f(h1b)) << 16);
      lw1 = (unsigned)f2bf(z[2] - bf2f(h2b)) | ((unsigned)f2bf(z[3] - bf2f(h3b)) << 16);
    }
    if (lane < 32) {
      int widx = (2 * p) ^ ((row & 7) << 2);  // XOR swizzle, preserves word pairing
      *(uint2*)&Ah32[row * 64 + widx] = uint2{hw0, hw1};
      *(uint2*)&Al32[row * 64 + widx] = uint2{lw0, lw1};
    }
    ecur = enxt;
  }
  __syncthreads();
  // B-frags for this wave's 16-col tile of W2 ([64][128] bf16 planes)
  const int colB = wid * 16 + (lane & 15);
  const int koff = (lane >> 4) * 8;
  short8 bh[4], bl[4];
#pragma unroll
  for (int ks = 0; ks < 4; ++ks) {
    bh[ks] = *(const short8*)(w2h + (size_t)colB * 128 + ks * 32 + koff);
    bl[ks] = *(const short8*)(w2l + (size_t)colB * 128 + ks * 32 + koff);
  }
  const int arow = lane & 15, ac = lane >> 4;
  f32x4 acc = {};
#pragma unroll
  for (int ks = 0; ks < 4; ++ks) {
    int bidx = arow * 64 + ((ks * 16 + ac * 4) ^ ((arow & 7) << 2));
    short8 ah = *(const short8*)(Ah32 + bidx);
    short8 al = *(const short8*)(Al32 + bidx);
    acc = __builtin_amdgcn_mfma_f32_16x16x32_bf16(ah, bh[ks], acc, 0, 0, 0);
    acc = __builtin_amdgcn_mfma_f32_16x16x32_bf16(ah, bl[ks], acc, 0, 0, 0);
    acc = __builtin_amdgcn_mfma_f32_16x16x32_bf16(al, bh[ks], acc, 0, 0, 0);
  }
  const int crow = (lane >> 4) * 4;
  const int col = wid * 16 + (lane & 15);
#pragma unroll
  for (int j = 0; j < 4; ++j) {
    int node = base + crow + j;
    if (node < M) h2[(size_t)node * 64 + col] = (_Float16)acc[j];
  }
}

// ---------------- agg64+matvec: fp16 h2 gather, 4 edges/wave-load ----------------
__global__ void k_agg64mv(const _Float16* __restrict__ h2, const int* __restrict__ offs,
                          const int2* __restrict__ esw, const float* __restrict__ nd,
                          const float* __restrict__ b2, const float* __restrict__ W3,
                          const float* __restrict__ ns, float* __restrict__ h3, int M) {
  __shared__ int2 emeta[4][64];
  const int lane = threadIdx.x & 63, wid = threadIdx.x >> 6;
  const int wave = blockIdx.x * (blockDim.x >> 6) + wid;
  const int nb0 = wave * 4;
  if (nb0 >= M) return;
  const uint2* hp = (const uint2*)h2;  // 8B = 4 fp16
  const int p = lane & 15;
  const int q4 = lane >> 4;
  f32x4 bv = ((const f32x4*)b2)[p];
  f32x4 w3v = ((const f32x4*)W3)[p];
  int ov = offs[min(nb0 + min(lane, 5), M)];
  int S0[4], S1[4];
#pragma unroll
  for (int q = 0; q < 4; ++q) { S0[q] = rdlane_i(ov, q); S1[q] = rdlane_i(ov, q + 1); }
  int2 ecur{0, 0};
  { int kk = S0[0] + lane; if (kk < S1[0]) ecur = esw[kk]; }
#pragma unroll
  for (int q = 0; q < 4; ++q) {
    const int node = nb0 + q;
    int2 enxt{0, 0};
    if (q < 3) { int kk = S0[q + 1] + lane; if (kk < S1[q + 1]) enxt = esw[kk]; }
    if (node < M) {
      const int s0 = S0[q], s1 = S1[q];
      f32x4 acc = {};
      int2 e = ecur;
      for (int bb = s0; bb < s1; bb += 64) {
        if (bb != s0) { int kk = bb + lane; e = (kk < s1) ? esw[kk] : int2{0, 0}; }
        emeta[wid][lane] = e;
        int cnt = min(64, s1 - bb);
        for (int jj = 0; jj < cnt; jj += 32) {
          int2 em[8];
          uint2 v[8];
#pragma unroll
          for (int u = 0; u < 8; ++u) em[u] = emeta[wid][jj + 4 * u + q4];
#pragma unroll
          for (int u = 0; u < 8; ++u)
            v[u] = hp[(size_t)(unsigned)em[u].x * 16 + p];
          __builtin_amdgcn_sched_barrier(0);
#pragma unroll
          for (int u = 0; u < 8; ++u) {
            float wu = __builtin_bit_cast(float, em[u].y);
            h16x4 hv = __builtin_bit_cast(h16x4, v[u]);
            acc[0] += (float)hv[0] * wu;
            acc[1] += (float)hv[1] * wu;
            acc[2] += (float)hv[2] * wu;
            acc[3] += (float)hv[3] * wu;
          }
        }
      }
#pragma unroll
      for (int i = 0; i < 4; ++i) {
        acc[i] += __shfl_xor(acc[i], 16);
        acc[i] += __shfl_xor(acc[i], 32);
      }
      float ndv = nd[node];
      float dp = 0.f;
#pragma unroll
      for (int i = 0; i < 4; ++i) dp += fmaxf(acc[i] * ndv + bv[i], 0.f) * w3v[i];
#pragma unroll
      for (int d = 8; d; d >>= 1) dp += __shfl_xor(dp, d);
      if (lane == 0) h3[node] = dp * ns[node];
    }
    ecur = enxt;
  }
}

// ---------------- final scalar aggregation: 16-deep batched gathers ----------------
__launch_bounds__(256)
__global__ void k_aggfin(const float* __restrict__ h3, const int* __restrict__ offs,
                         const int2* __restrict__ esw, const float* __restrict__ nd,
                         const float* __restrict__ b3, float* __restrict__ out, int M) {
  int i = blockIdx.x * blockDim.x + threadIdx.x;
  if (i >= M) return;
  int s0 = offs[i], s1 = offs[i + 1];
  float acc = 0.f;
  for (int k0 = s0; k0 < s1; k0 += 16) {
    int nn = min(16, s1 - k0);
    int2 e[16];
    float hv[16];
#pragma unroll
    for (int u = 0; u < 16; ++u) e[u] = esw[k0 + min(u, nn - 1)];
#pragma unroll
    for (int u = 0; u < 16; ++u) hv[u] = h3[e[u].x];
    __builtin_amdgcn_sched_barrier(0);
#pragma unroll
    for (int u = 0; u < 16; ++u)
      if (u < nn) acc += hv[u] * __builtin_bit_cast(float, e[u].y);
  }
  out[i] = acc * nd[i] + b3[0];
}

extern "C" void kernel_launch(void* const* d_in, const int* in_sizes, int n_in,
                              void* d_out, int out_size, void* d_ws, size_t ws_size,
                              hipStream_t stream) {
  const float* b_z = (const float*)d_in[0];
  const int*   src = (const int*)d_in[1];
  const int*   dst = (const int*)d_in[2];
  const float* ew  = (const float*)d_in[3];
  const float* W1  = (const float*)d_in[5];
  const float* b1  = (const float*)d_in[6];
  const float* W2  = (const float*)d_in[7];
  const float* b2  = (const float*)d_in[8];
  const float* W3  = (const float*)d_in[9];
  const float* b3  = (const float*)d_in[10];
  const int N = in_sizes[0] / D0;
  const int E = in_sizes[1];
  float* out = (float*)d_out;

  char* ws = (char*)d_ws;
  size_t off_b = 0;
  auto alloc = [&](size_t bytes) -> void* {
    void* p = ws + off_b;
    off_b += (bytes + 255) & ~(size_t)255;
    return p;
  };
  const int nbk = (E + EBLK - 1) / EBLK;
  int*   bc_s    = (int*)alloc((size_t)nbk * NB * 4);
  int*   bc_d    = (int*)alloc((size_t)nbk * NB * 4);
  int*   bt_s    = (int*)alloc((size_t)NB * 4);
  int*   bt_d    = (int*)alloc((size_t)NB * 4);
  int*   cbase_s = (int*)alloc((size_t)(NB + 1) * 4);
  int*   cbase_d = (int*)alloc((size_t)(NB + 1) * 4);
  int*   offs    = (int*)alloc((size_t)(N + 1) * 4);
  int2*  esw     = (int2*)alloc((size_t)E * 8);
  float* nsrc    = (float*)alloc((size_t)N * 4);
  float* ndst    = (float*)alloc((size_t)N * 4);
  _Float16* h1   = (_Float16*)alloc((size_t)N * D1 * 2);  // 25.6 MB (fp16)
  _Float16* h2   = (_Float16*)alloc((size_t)N * D2 * 2);  // 12.8 MB (fp16)
  float* h3      = (float*)alloc((size_t)N * 4);
  short* wt1h    = (short*)alloc((size_t)D0 * D1 * 2);
  short* wt1l    = (short*)alloc((size_t)D0 * D1 * 2);
  short* wt2h    = (short*)alloc((size_t)D1 * D2 * 2);
  short* wt2l    = (short*)alloc((size_t)D1 * D2 * 2);
  // partition records alias h1 (both dead before GEMM1 writes h1; 12.8+6.4 < 25.6MB)
  int2*  recs_d = (int2*)h1;                              // E*8 = 12.8 MB
  int*   recs_s = (int*)((char*)h1 + ((size_t)13 << 20)); // E*4 = 6.4 MB @ +13MB

  // --- CSR build (atomic-free, fully parallel) ---
  k_chist2<<<nbk, 256, 0, stream>>>(src, dst, bc_s, bc_d, E);
  k_binscan<<<dim3(NB / 16, 2), 256, 0, stream>>>(bc_s, bt_s, bc_d, bt_d, nbk);
  k_btscan<<<2, 1024, 0, stream>>>(bt_s, cbase_s, bt_d, cbase_d, &offs[N], E);
  k_cpart2<<<nbk, 256, 0, stream>>>(src, dst, ew, bc_s, cbase_s, bc_d, cbase_d,
                                    recs_s, recs_d, E);
  k_finecomb<<<NB, 256, 0, stream>>>(recs_d, cbase_d, recs_s, cbase_s, esw, offs,
                                     ndst, nsrc, N);
  k_wsplit2<<<(D0 * D1 + D1 * D2 + 255) / 256, 256, 0, stream>>>(W1, wt1h, wt1l,
                                                                 W2, wt2h, wt2l);

  // layer 1: 256 -> 128 (MFMA, fp16 out)
  k_gemm_mfma<D0, D1, 2, 2><<<(N + 127) / 128, 256, 0, stream>>>(b_z, nsrc, wt1h, wt1l, h1, N);
  // layer-1 agg (fp16 gather) + layer-2 projection fused (writes fp16 h2, no z1)
  k_agg128f<<<(N + 15) / 16, 256, 0, stream>>>(h1, offs, esw, ndst, b1, nsrc,
                                               wt2h, wt2l, h2, N);
  // layer-2 agg fused with layer-3 projection (64->1 matvec), fp16 gathers
  k_agg64mv<<<(N + 15) / 16, 256, 0, stream>>>(h2, offs, esw, ndst, b2, W3, nsrc, h3, N);
  // final scalar aggregation
  k_aggfin<<<(N + 255) / 256, 256, 0, stream>>>(h3, offs, esw, ndst, b3, out, N);
}